// Round 4
// baseline (1284.251 us; speedup 1.0000x reference)
//
#include <hip/hip_runtime.h>

#define NN 100000
#define NE 1600000

#define SCAN_TILE 1024
#define NTILES ((NN + SCAN_TILE - 1) / SCAN_TILE)  // 98

// ---------------- CSR build ----------------

__global__ __launch_bounds__(256) void count_kernel(const int* __restrict__ dst,
                                                    int* __restrict__ cnt) {
  int e = blockIdx.x * 256 + threadIdx.x;
  atomicAdd(&cnt[dst[e]], 1);
}

__global__ __launch_bounds__(256) void scan_reduce(const int* __restrict__ cnt,
                                                   int* __restrict__ tile_sum) {
  __shared__ int ws[4];
  int t = threadIdx.x;
  int base = blockIdx.x * SCAN_TILE + t * 4;
  int s = 0;
#pragma unroll
  for (int i = 0; i < 4; ++i) {
    int idx = base + i;
    if (idx < NN) s += cnt[idx];
  }
#pragma unroll
  for (int off = 32; off; off >>= 1) s += __shfl_down(s, off, 64);
  if ((t & 63) == 0) ws[t >> 6] = s;
  __syncthreads();
  if (t == 0) tile_sum[blockIdx.x] = ws[0] + ws[1] + ws[2] + ws[3];
}

__global__ __launch_bounds__(128) void scan_tiles(const int* __restrict__ tile_sum,
                                                  int* __restrict__ tile_off,
                                                  int* __restrict__ row_ptr) {
  __shared__ int part[128];
  int t = threadIdx.x;
  int v = (t < NTILES) ? tile_sum[t] : 0;
  part[t] = v;
  __syncthreads();
  for (int off = 1; off < 128; off <<= 1) {
    int u = (t >= off) ? part[t - off] : 0;
    __syncthreads();
    part[t] += u;
    __syncthreads();
  }
  if (t < NTILES) tile_off[t] = part[t] - v;
  if (t == 127) row_ptr[NN] = part[127];
}

__global__ __launch_bounds__(256) void scan_apply(const int* __restrict__ cnt,
                                                  const int* __restrict__ tile_off,
                                                  int* __restrict__ row_ptr,
                                                  int* __restrict__ cursor,
                                                  float* __restrict__ deg_inv) {
  __shared__ int part[256];
  int t = threadIdx.x;
  int base = blockIdx.x * SCAN_TILE + t * 4;
  int c[4];
#pragma unroll
  for (int i = 0; i < 4; ++i) {
    int idx = base + i;
    c[i] = (idx < NN) ? cnt[idx] : 0;
  }
  int s = c[0] + c[1] + c[2] + c[3];
  part[t] = s;
  __syncthreads();
  for (int off = 1; off < 256; off <<= 1) {
    int u = (t >= off) ? part[t - off] : 0;
    __syncthreads();
    part[t] += u;
    __syncthreads();
  }
  int run = tile_off[blockIdx.x] + part[t] - s;
#pragma unroll
  for (int i = 0; i < 4; ++i) {
    int idx = base + i;
    if (idx < NN) {
      row_ptr[idx] = run;
      cursor[idx] = run;
      deg_inv[idx] = 1.0f / (float)(c[i] > 1 ? c[i] : 1);
      run += c[i];
    }
  }
}

__global__ __launch_bounds__(256) void fill_kernel(const int* __restrict__ src,
                                                   const int* __restrict__ dst,
                                                   int* __restrict__ cursor,
                                                   int* __restrict__ col) {
  int e = blockIdx.x * 256 + threadIdx.x;
  int pos = atomicAdd(&cursor[dst[e]], 1);
  col[pos] = src[e];
}

// ---------------- fused layer: gather-mean + dual GEMM + projection ----------------
// 64 nodes per 256-thread block. LDS 59.4KB -> 2 blocks/CU.
// flags bit0: first layer (init out with bp); bit1: write hn to global.

#define LP 68  // padded leading dim: float4-aligned, banks (4m+k)%32 -> worst 2-way (free)

__global__ __launch_bounds__(256) void fused_layer(
    const float* __restrict__ h,
    const int* __restrict__ row_ptr, const int* __restrict__ col,
    const float* __restrict__ deginv,
    const float* __restrict__ Wl, const float* __restrict__ bl,
    const float* __restrict__ Wr, const float* __restrict__ Wp,
    const float* __restrict__ bp,
    float* __restrict__ hn, float* __restrict__ out, int flags) {
  __shared__ float aS[64][LP];
  __shared__ float hS[64][LP];
  __shared__ float WlS[32 * 64];
  __shared__ float WrS[32 * 64];
  __shared__ float WpS[64 * 32];
  int tid = threadIdx.x;
  int base = blockIdx.x * 64;
  int wave = tid >> 6, lane = tid & 63;

  // stage own h rows (for lin_r): 1024 float4s / 256 thr = 4 each
#pragma unroll
  for (int j = 0; j < 4; ++j) {
    int idx = tid + j * 256;
    int r = idx >> 4, c4 = (idx & 15) << 2;
    int node = base + r;
    float4 v = make_float4(0.f, 0.f, 0.f, 0.f);
    if (node < NN) v = *(const float4*)(h + (size_t)node * 64 + c4);
    *(float4*)&hS[r][c4] = v;
  }
  // stage Wp (64x32)
#pragma unroll
  for (int j = 0; j < 2; ++j)
    ((float4*)WpS)[tid + j * 256] = ((const float4*)Wp)[tid + j * 256];

  // gather: wave per node (lane = feature), 16 nodes per wave, 4-deep unroll
  for (int i = 0; i < 16; ++i) {
    int n = wave * 16 + i;
    int node = base + n;
    float acc = 0.f;
    if (node < NN) {
      int beg = row_ptr[node], end = row_ptr[node + 1];
      int e = beg;
      for (; e + 4 <= end; e += 4) {
        int s0 = col[e], s1 = col[e + 1], s2 = col[e + 2], s3 = col[e + 3];
        float v0 = h[(size_t)s0 * 64 + lane];
        float v1 = h[(size_t)s1 * 64 + lane];
        float v2 = h[(size_t)s2 * 64 + lane];
        float v3 = h[(size_t)s3 * 64 + lane];
        acc += (v0 + v1) + (v2 + v3);
      }
      for (; e < end; ++e) acc += h[(size_t)col[e] * 64 + lane];
      acc *= deginv[node];
    }
    aS[n][lane] = acc;
  }

  // dual GEMM: hn = aS@Wl + bl + hS@Wr ; thread = 2 nodes x 8 cols
  int tx = tid & 7, ty = tid >> 3;
  int m0 = ty * 2, c0 = tx * 8;
  float acc[2][8];
  {
    float4 b0 = *(const float4*)(bl + c0);
    float4 b1 = *(const float4*)(bl + c0 + 4);
#pragma unroll
    for (int m = 0; m < 2; ++m) {
      acc[m][0] = b0.x; acc[m][1] = b0.y; acc[m][2] = b0.z; acc[m][3] = b0.w;
      acc[m][4] = b1.x; acc[m][5] = b1.y; acc[m][6] = b1.z; acc[m][7] = b1.w;
    }
  }

  for (int p = 0; p < 2; ++p) {
    __syncthreads();  // p=0: fences gather/hS/Wp staging; p=1: fences k-loop reads of W
#pragma unroll
    for (int j = 0; j < 2; ++j) {
      int idx = tid + j * 256;
      ((float4*)WlS)[idx] = ((const float4*)(Wl + p * 2048))[idx];
      ((float4*)WrS)[idx] = ((const float4*)(Wr + p * 2048))[idx];
    }
    __syncthreads();
#pragma unroll 8
    for (int k = 0; k < 32; ++k) {
      int kg = p * 32 + k;
      float4 l0 = *(const float4*)&WlS[k * 64 + c0];
      float4 l1 = *(const float4*)&WlS[k * 64 + c0 + 4];
      float4 r0 = *(const float4*)&WrS[k * 64 + c0];
      float4 r1 = *(const float4*)&WrS[k * 64 + c0 + 4];
#pragma unroll
      for (int m = 0; m < 2; ++m) {
        float a = aS[m0 + m][kg];
        float hh = hS[m0 + m][kg];
        acc[m][0] += a * l0.x + hh * r0.x;
        acc[m][1] += a * l0.y + hh * r0.y;
        acc[m][2] += a * l0.z + hh * r0.z;
        acc[m][3] += a * l0.w + hh * r0.w;
        acc[m][4] += a * l1.x + hh * r1.x;
        acc[m][5] += a * l1.y + hh * r1.y;
        acc[m][6] += a * l1.z + hh * r1.z;
        acc[m][7] += a * l1.w + hh * r1.w;
      }
    }
  }

  // write hn to global (skipped on last layer)
  if (flags & 2) {
#pragma unroll
    for (int m = 0; m < 2; ++m) {
      int node = base + m0 + m;
      if (node < NN) {
        *(float4*)(hn + (size_t)node * 64 + c0) =
            make_float4(acc[m][0], acc[m][1], acc[m][2], acc[m][3]);
        *(float4*)(hn + (size_t)node * 64 + c0 + 4) =
            make_float4(acc[m][4], acc[m][5], acc[m][6], acc[m][7]);
      }
    }
  }

  __syncthreads();  // all GEMM reads of aS done
  // stash hn tile into aS (reuse) for projection
#pragma unroll
  for (int m = 0; m < 2; ++m) {
    *(float4*)&aS[m0 + m][c0] =
        make_float4(acc[m][0], acc[m][1], acc[m][2], acc[m][3]);
    *(float4*)&aS[m0 + m][c0 + 4] =
        make_float4(acc[m][4], acc[m][5], acc[m][6], acc[m][7]);
  }
  __syncthreads();

  // projection: out[node] (+)= hn_row @ Wp ; 4 threads per node, 8 cols each
  int nloc = tid >> 2;
  int pc0 = (tid & 3) * 8;
  int node = base + nloc;
  if (node < NN) {
    float pa[8];
    {
      const float* src = (flags & 1) ? (bp + pc0) : (out + (size_t)node * 32 + pc0);
      float4 p0 = *(const float4*)src;
      float4 p1 = *(const float4*)(src + 4);
      pa[0] = p0.x; pa[1] = p0.y; pa[2] = p0.z; pa[3] = p0.w;
      pa[4] = p1.x; pa[5] = p1.y; pa[6] = p1.z; pa[7] = p1.w;
    }
#pragma unroll 4
    for (int k = 0; k < 64; ++k) {
      float a = aS[nloc][k];
      float4 w0 = *(const float4*)&WpS[k * 32 + pc0];
      float4 w1 = *(const float4*)&WpS[k * 32 + pc0 + 4];
      pa[0] += a * w0.x; pa[1] += a * w0.y; pa[2] += a * w0.z; pa[3] += a * w0.w;
      pa[4] += a * w1.x; pa[5] += a * w1.y; pa[6] += a * w1.z; pa[7] += a * w1.w;
    }
    *(float4*)(out + (size_t)node * 32 + pc0) = make_float4(pa[0], pa[1], pa[2], pa[3]);
    *(float4*)(out + (size_t)node * 32 + pc0 + 4) = make_float4(pa[4], pa[5], pa[6], pa[7]);
  }
}

// ---------------- launch ----------------

extern "C" void kernel_launch(void* const* d_in, const int* in_sizes, int n_in,
                              void* d_out, int out_size, void* d_ws, size_t ws_size,
                              hipStream_t stream) {
  const float* x  = (const float*)d_in[0];
  const int*   ei = (const int*)d_in[1];   // [2, NE] int32
  const float* Wl = (const float*)d_in[2];
  const float* bl = (const float*)d_in[3];
  const float* Wr = (const float*)d_in[4];
  const float* Wp = (const float*)d_in[5];
  const float* bp = (const float*)d_in[6];
  float* out = (float*)d_out;

  char* ws = (char*)d_ws;
  size_t off = 0;
  auto alloc = [&](size_t bytes) {
    void* p = ws + off;
    off = (off + bytes + 255) & ~(size_t)255;
    return p;
  };
  int*   cnt      = (int*)alloc((size_t)NN * 4);
  int*   row_ptr  = (int*)alloc(((size_t)NN + 1) * 4);
  int*   cursor   = (int*)alloc((size_t)NN * 4);
  float* deginv   = (float*)alloc((size_t)NN * 4);
  int*   col      = (int*)alloc((size_t)NE * 4);
  int*   tile_sum = (int*)alloc((size_t)NTILES * 4);
  int*   tile_off = (int*)alloc((size_t)NTILES * 4);
  float* hA       = (float*)alloc((size_t)NN * 64 * 4);
  float* hB       = (float*)alloc((size_t)NN * 64 * 4);

  hipMemsetAsync(cnt, 0, (size_t)NN * 4, stream);
  count_kernel<<<NE / 256, 256, 0, stream>>>(ei + NE, cnt);
  scan_reduce<<<NTILES, 256, 0, stream>>>(cnt, tile_sum);
  scan_tiles<<<1, 128, 0, stream>>>(tile_sum, tile_off, row_ptr);
  scan_apply<<<NTILES, 256, 0, stream>>>(cnt, tile_off, row_ptr, cursor, deginv);
  fill_kernel<<<NE / 256, 256, 0, stream>>>(ei, ei + NE, cursor, col);

  const float* cur = x;
  float* bufs[2] = {hA, hB};
  int nblk = (NN + 63) / 64;
  for (int l = 0; l < 4; ++l) {
    float* nxt = bufs[l & 1];
    int flags = (l == 0 ? 1 : 0) | (l < 3 ? 2 : 0);
    fused_layer<<<nblk, 256, 0, stream>>>(cur, row_ptr, col, deginv,
                                          Wl + l * 4096, bl + l * 64,
                                          Wr + l * 4096, Wp + l * 2048, bp,
                                          nxt, out, flags);
    cur = nxt;
  }
}

// Round 7
// 766.682 us; speedup vs baseline: 1.6751x; 1.6751x over previous
//
#include <hip/hip_runtime.h>

#define NN 100000
#define NE 1600000

#define SCAN_TILE 1024
#define NTILES ((NN + SCAN_TILE - 1) / SCAN_TILE)  // 98

// ---------------- CSR build ----------------

__global__ __launch_bounds__(256) void count_kernel(const int* __restrict__ dst,
                                                    int* __restrict__ cnt) {
  int e = blockIdx.x * 256 + threadIdx.x;
  atomicAdd(&cnt[dst[e]], 1);
}

__global__ __launch_bounds__(256) void scan_reduce(const int* __restrict__ cnt,
                                                   int* __restrict__ tile_sum) {
  __shared__ int ws[4];
  int t = threadIdx.x;
  int base = blockIdx.x * SCAN_TILE + t * 4;
  int s = 0;
#pragma unroll
  for (int i = 0; i < 4; ++i) {
    int idx = base + i;
    if (idx < NN) s += cnt[idx];
  }
#pragma unroll
  for (int off = 32; off; off >>= 1) s += __shfl_down(s, off, 64);
  if ((t & 63) == 0) ws[t >> 6] = s;
  __syncthreads();
  if (t == 0) tile_sum[blockIdx.x] = ws[0] + ws[1] + ws[2] + ws[3];
}

__global__ __launch_bounds__(128) void scan_tiles(const int* __restrict__ tile_sum,
                                                  int* __restrict__ tile_off,
                                                  int* __restrict__ row_ptr) {
  __shared__ int part[128];
  int t = threadIdx.x;
  int v = (t < NTILES) ? tile_sum[t] : 0;
  part[t] = v;
  __syncthreads();
  for (int off = 1; off < 128; off <<= 1) {
    int u = (t >= off) ? part[t - off] : 0;
    __syncthreads();
    part[t] += u;
    __syncthreads();
  }
  if (t < NTILES) tile_off[t] = part[t] - v;
  if (t == 127) row_ptr[NN] = part[127];
}

__global__ __launch_bounds__(256) void scan_apply(const int* __restrict__ cnt,
                                                  const int* __restrict__ tile_off,
                                                  int* __restrict__ row_ptr,
                                                  int* __restrict__ cursor,
                                                  float* __restrict__ deg_inv) {
  __shared__ int part[256];
  int t = threadIdx.x;
  int base = blockIdx.x * SCAN_TILE + t * 4;
  int c[4];
#pragma unroll
  for (int i = 0; i < 4; ++i) {
    int idx = base + i;
    c[i] = (idx < NN) ? cnt[idx] : 0;
  }
  int s = c[0] + c[1] + c[2] + c[3];
  part[t] = s;
  __syncthreads();
  for (int off = 1; off < 256; off <<= 1) {
    int u = (t >= off) ? part[t - off] : 0;
    __syncthreads();
    part[t] += u;
    __syncthreads();
  }
  int run = tile_off[blockIdx.x] + part[t] - s;
#pragma unroll
  for (int i = 0; i < 4; ++i) {
    int idx = base + i;
    if (idx < NN) {
      row_ptr[idx] = run;
      cursor[idx] = run;
      deg_inv[idx] = 1.0f / (float)(c[i] > 1 ? c[i] : 1);
      run += c[i];
    }
  }
}

__global__ __launch_bounds__(256) void fill_kernel(const int* __restrict__ src,
                                                   const int* __restrict__ dst,
                                                   int* __restrict__ cursor,
                                                   int* __restrict__ col) {
  int e = blockIdx.x * 256 + threadIdx.x;
  int pos = atomicAdd(&cursor[dst[e]], 1);
  col[pos] = src[e];
}

// ---------------- mean aggregation: wave per node, shfl-broadcast ids, MLP=8 ----------------

__global__ __launch_bounds__(256) void agg_kernel(const float* __restrict__ h,
                                                  const int* __restrict__ row_ptr,
                                                  const int* __restrict__ col,
                                                  const float* __restrict__ deg_inv,
                                                  float* __restrict__ agg) {
  int w = (int)((blockIdx.x * 256u + threadIdx.x) >> 6);
  int lane = threadIdx.x & 63;
  if (w >= NN) return;
  int beg = row_ptr[w], end = row_ptr[w + 1];
  float acc = 0.f;
  int e = beg;
  while (e < end) {
    int chunk = end - e;
    if (chunk > 64) chunk = 64;
    // one coalesced load grabs the whole id window; lanes past chunk clamp
    int cv = col[e + (lane < chunk ? lane : chunk - 1)];
    int i = 0;
    for (; i + 8 <= chunk; i += 8) {
      int s0 = __shfl(cv, i + 0, 64), s1 = __shfl(cv, i + 1, 64);
      int s2 = __shfl(cv, i + 2, 64), s3 = __shfl(cv, i + 3, 64);
      int s4 = __shfl(cv, i + 4, 64), s5 = __shfl(cv, i + 5, 64);
      int s6 = __shfl(cv, i + 6, 64), s7 = __shfl(cv, i + 7, 64);
      float v0 = h[(size_t)s0 * 64 + lane];
      float v1 = h[(size_t)s1 * 64 + lane];
      float v2 = h[(size_t)s2 * 64 + lane];
      float v3 = h[(size_t)s3 * 64 + lane];
      float v4 = h[(size_t)s4 * 64 + lane];
      float v5 = h[(size_t)s5 * 64 + lane];
      float v6 = h[(size_t)s6 * 64 + lane];
      float v7 = h[(size_t)s7 * 64 + lane];
      acc += ((v0 + v1) + (v2 + v3)) + ((v4 + v5) + (v6 + v7));
    }
    for (; i < chunk; ++i) {
      int s = __shfl(cv, i, 64);
      acc += h[(size_t)s * 64 + lane];
    }
    e += chunk;
  }
  agg[(size_t)w * 64 + lane] = acc * deg_inv[w];
}

// ---------------- fused layer GEMM + projection ----------------
// hn = agg@Wl + bl + h@Wr ; out (+)= hn @ Wp (+ bp on layer 0)
// 64 nodes / 256-thread block. LDS 50KB -> 3 blocks/CU (12 waves).
// flags bit0: first layer (init out with bp); bit1: write hn to global.

#define LP 68  // padded leading dim: float4-aligned; worst-case 2-way bank alias (free)

__global__ __launch_bounds__(256) void layer_proj(
    const float* __restrict__ agg, const float* __restrict__ h,
    const float* __restrict__ Wl, const float* __restrict__ bl,
    const float* __restrict__ Wr, const float* __restrict__ Wp,
    const float* __restrict__ bp,
    float* __restrict__ hn, float* __restrict__ out, int flags) {
  __shared__ float aS[64][LP];
  __shared__ float hS[64][LP];
  __shared__ float WlS[32 * 64];
  __shared__ float WrS[32 * 64];
  int tid = threadIdx.x;
  int base = blockIdx.x * 64;

  // stage agg + h tiles (4 float4s each per thread)
#pragma unroll
  for (int j = 0; j < 4; ++j) {
    int idx = tid + j * 256;
    int r = idx >> 4, c4 = (idx & 15) << 2;
    int node = base + r;
    float4 av = make_float4(0.f, 0.f, 0.f, 0.f), hv = av;
    if (node < NN) {
      av = *(const float4*)(agg + (size_t)node * 64 + c4);
      hv = *(const float4*)(h + (size_t)node * 64 + c4);
    }
    *(float4*)&aS[r][c4] = av;
    *(float4*)&hS[r][c4] = hv;
  }

  int tx = tid & 7, ty = tid >> 3;
  int m0 = ty * 2, c0 = tx * 8;
  float acc[2][8];
  {
    float4 b0 = *(const float4*)(bl + c0);
    float4 b1 = *(const float4*)(bl + c0 + 4);
#pragma unroll
    for (int m = 0; m < 2; ++m) {
      acc[m][0] = b0.x; acc[m][1] = b0.y; acc[m][2] = b0.z; acc[m][3] = b0.w;
      acc[m][4] = b1.x; acc[m][5] = b1.y; acc[m][6] = b1.z; acc[m][7] = b1.w;
    }
  }

  for (int p = 0; p < 2; ++p) {
    __syncthreads();  // p=0 fences tile staging; p=1 fences prior W reads
#pragma unroll
    for (int j = 0; j < 2; ++j) {
      int idx = tid + j * 256;
      ((float4*)WlS)[idx] = ((const float4*)(Wl + p * 2048))[idx];
      ((float4*)WrS)[idx] = ((const float4*)(Wr + p * 2048))[idx];
    }
    __syncthreads();
#pragma unroll 8
    for (int k = 0; k < 32; ++k) {
      int kg = p * 32 + k;
      float4 l0 = *(const float4*)&WlS[k * 64 + c0];
      float4 l1 = *(const float4*)&WlS[k * 64 + c0 + 4];
      float4 r0 = *(const float4*)&WrS[k * 64 + c0];
      float4 r1 = *(const float4*)&WrS[k * 64 + c0 + 4];
#pragma unroll
      for (int m = 0; m < 2; ++m) {
        float a = aS[m0 + m][kg];
        float hh = hS[m0 + m][kg];
        acc[m][0] += a * l0.x + hh * r0.x;
        acc[m][1] += a * l0.y + hh * r0.y;
        acc[m][2] += a * l0.z + hh * r0.z;
        acc[m][3] += a * l0.w + hh * r0.w;
        acc[m][4] += a * l1.x + hh * r1.x;
        acc[m][5] += a * l1.y + hh * r1.y;
        acc[m][6] += a * l1.z + hh * r1.z;
        acc[m][7] += a * l1.w + hh * r1.w;
      }
    }
  }

  // write hn (skipped on last layer)
  if (flags & 2) {
#pragma unroll
    for (int m = 0; m < 2; ++m) {
      int node = base + m0 + m;
      if (node < NN) {
        *(float4*)(hn + (size_t)node * 64 + c0) =
            make_float4(acc[m][0], acc[m][1], acc[m][2], acc[m][3]);
        *(float4*)(hn + (size_t)node * 64 + c0 + 4) =
            make_float4(acc[m][4], acc[m][5], acc[m][6], acc[m][7]);
      }
    }
  }

  __syncthreads();  // all GEMM reads of aS done
  // stash hn tile into aS for the projection
#pragma unroll
  for (int m = 0; m < 2; ++m) {
    *(float4*)&aS[m0 + m][c0] =
        make_float4(acc[m][0], acc[m][1], acc[m][2], acc[m][3]);
    *(float4*)&aS[m0 + m][c0 + 4] =
        make_float4(acc[m][4], acc[m][5], acc[m][6], acc[m][7]);
  }
  __syncthreads();

  // projection: 4 threads per node, 8 cols each; Wp via L1 (8KB, hot)
  int nloc = tid >> 2;
  int pc0 = (tid & 3) * 8;
  int node = base + nloc;
  if (node < NN) {
    float pa[8];
    {
      const float* src = (flags & 1) ? (bp + pc0) : (out + (size_t)node * 32 + pc0);
      float4 p0 = *(const float4*)src;
      float4 p1 = *(const float4*)(src + 4);
      pa[0] = p0.x; pa[1] = p0.y; pa[2] = p0.z; pa[3] = p0.w;
      pa[4] = p1.x; pa[5] = p1.y; pa[6] = p1.z; pa[7] = p1.w;
    }
#pragma unroll 8
    for (int k = 0; k < 64; ++k) {
      float a = aS[nloc][k];
      float4 w0 = *(const float4*)(Wp + k * 32 + pc0);
      float4 w1 = *(const float4*)(Wp + k * 32 + pc0 + 4);
      pa[0] += a * w0.x; pa[1] += a * w0.y; pa[2] += a * w0.z; pa[3] += a * w0.w;
      pa[4] += a * w1.x; pa[5] += a * w1.y; pa[6] += a * w1.z; pa[7] += a * w1.w;
    }
    *(float4*)(out + (size_t)node * 32 + pc0) = make_float4(pa[0], pa[1], pa[2], pa[3]);
    *(float4*)(out + (size_t)node * 32 + pc0 + 4) = make_float4(pa[4], pa[5], pa[6], pa[7]);
  }
}

// ---------------- launch ----------------

extern "C" void kernel_launch(void* const* d_in, const int* in_sizes, int n_in,
                              void* d_out, int out_size, void* d_ws, size_t ws_size,
                              hipStream_t stream) {
  const float* x  = (const float*)d_in[0];
  const int*   ei = (const int*)d_in[1];   // [2, NE] int32
  const float* Wl = (const float*)d_in[2];
  const float* bl = (const float*)d_in[3];
  const float* Wr = (const float*)d_in[4];
  const float* Wp = (const float*)d_in[5];
  const float* bp = (const float*)d_in[6];
  float* out = (float*)d_out;

  char* ws = (char*)d_ws;
  size_t off = 0;
  auto alloc = [&](size_t bytes) {
    void* p = ws + off;
    off = (off + bytes + 255) & ~(size_t)255;
    return p;
  };
  int*   cnt      = (int*)alloc((size_t)NN * 4);
  int*   row_ptr  = (int*)alloc(((size_t)NN + 1) * 4);
  int*   cursor   = (int*)alloc((size_t)NN * 4);
  float* deginv   = (float*)alloc((size_t)NN * 4);
  int*   col      = (int*)alloc((size_t)NE * 4);
  int*   tile_sum = (int*)alloc((size_t)NTILES * 4);
  int*   tile_off = (int*)alloc((size_t)NTILES * 4);
  float* agg      = (float*)alloc((size_t)NN * 64 * 4);
  float* hA       = (float*)alloc((size_t)NN * 64 * 4);
  float* hB       = (float*)alloc((size_t)NN * 64 * 4);

  hipMemsetAsync(cnt, 0, (size_t)NN * 4, stream);
  count_kernel<<<NE / 256, 256, 0, stream>>>(ei + NE, cnt);
  scan_reduce<<<NTILES, 256, 0, stream>>>(cnt, tile_sum);
  scan_tiles<<<1, 128, 0, stream>>>(tile_sum, tile_off, row_ptr);
  scan_apply<<<NTILES, 256, 0, stream>>>(cnt, tile_off, row_ptr, cursor, deginv);
  fill_kernel<<<NE / 256, 256, 0, stream>>>(ei, ei + NE, cursor, col);

  const float* cur = x;
  float* bufs[2] = {hA, hB};
  int nblk = (NN + 63) / 64;
  for (int l = 0; l < 4; ++l) {
    agg_kernel<<<(NN + 3) / 4, 256, 0, stream>>>(cur, row_ptr, col, deginv, agg);
    float* nxt = bufs[l & 1];
    int flags = (l == 0 ? 1 : 0) | (l < 3 ? 2 : 0);
    layer_proj<<<nblk, 256, 0, stream>>>(agg, cur, Wl + l * 4096, bl + l * 64,
                                         Wr + l * 4096, Wp + l * 2048, bp,
                                         nxt, out, flags);
    cur = nxt;
  }
}

// Round 9
// 673.629 us; speedup vs baseline: 1.9065x; 1.1381x over previous
//
#include <hip/hip_runtime.h>
#include <hip/hip_fp16.h>

#define NN 100000
#define NE 1600000

#define SCAN_TILE 1024
#define NTILES ((NN + SCAN_TILE - 1) / SCAN_TILE)  // 98

// CSR bucket sort params
#define NPB 512                          // nodes per bucket (pow2: bucket = dst>>9)
#define NBUK ((NN + NPB - 1) / NPB)      // 196
#define EPB 2048                         // edges per binA block
#define ABLK ((NE + EPB - 1) / EPB)      // 782
#define BCAP 10240                       // max edges per bucket (mean 8192, sd ~90)

// ---------------- degree count + row_ptr scan ----------------

__global__ __launch_bounds__(256) void count_kernel(const int* __restrict__ dst,
                                                    int* __restrict__ cnt) {
  int e = blockIdx.x * 256 + threadIdx.x;
  atomicAdd(&cnt[dst[e]], 1);
}

__global__ __launch_bounds__(256) void scan_reduce(const int* __restrict__ cnt,
                                                   int* __restrict__ tile_sum) {
  __shared__ int ws[4];
  int t = threadIdx.x;
  int base = blockIdx.x * SCAN_TILE + t * 4;
  int s = 0;
#pragma unroll
  for (int i = 0; i < 4; ++i) {
    int idx = base + i;
    if (idx < NN) s += cnt[idx];
  }
#pragma unroll
  for (int off = 32; off; off >>= 1) s += __shfl_down(s, off, 64);
  if ((t & 63) == 0) ws[t >> 6] = s;
  __syncthreads();
  if (t == 0) tile_sum[blockIdx.x] = ws[0] + ws[1] + ws[2] + ws[3];
}

__global__ __launch_bounds__(128) void scan_tiles(const int* __restrict__ tile_sum,
                                                  int* __restrict__ tile_off,
                                                  int* __restrict__ row_ptr) {
  __shared__ int part[128];
  int t = threadIdx.x;
  int v = (t < NTILES) ? tile_sum[t] : 0;
  part[t] = v;
  __syncthreads();
  for (int off = 1; off < 128; off <<= 1) {
    int u = (t >= off) ? part[t - off] : 0;
    __syncthreads();
    part[t] += u;
    __syncthreads();
  }
  if (t < NTILES) tile_off[t] = part[t] - v;
  if (t == 127) row_ptr[NN] = part[127];
}

__global__ __launch_bounds__(256) void scan_apply(const int* __restrict__ cnt,
                                                  const int* __restrict__ tile_off,
                                                  int* __restrict__ row_ptr,
                                                  float* __restrict__ deg_inv) {
  __shared__ int part[256];
  int t = threadIdx.x;
  int base = blockIdx.x * SCAN_TILE + t * 4;
  int c[4];
#pragma unroll
  for (int i = 0; i < 4; ++i) {
    int idx = base + i;
    c[i] = (idx < NN) ? cnt[idx] : 0;
  }
  int s = c[0] + c[1] + c[2] + c[3];
  part[t] = s;
  __syncthreads();
  for (int off = 1; off < 256; off <<= 1) {
    int u = (t >= off) ? part[t - off] : 0;
    __syncthreads();
    part[t] += u;
    __syncthreads();
  }
  int run = tile_off[blockIdx.x] + part[t] - s;
#pragma unroll
  for (int i = 0; i < 4; ++i) {
    int idx = base + i;
    if (idx < NN) {
      row_ptr[idx] = run;
      deg_inv[idx] = 1.0f / (float)(c[i] > 1 ? c[i] : 1);
      run += c[i];
    }
  }
}

// ---------------- two-pass binned CSR fill (coalesced col writes) ----------------

__global__ __launch_bounds__(256) void bcur_init(const int* __restrict__ row_ptr,
                                                 int* __restrict__ bucket_cur) {
  int t = blockIdx.x * 256 + threadIdx.x;
  if (t < NBUK) bucket_cur[t] = row_ptr[min(t * NPB, NN)];
}

// pass A: bin (src,dst) pairs by dst>>9 with LDS staging -> bucket-grouped writes
__global__ __launch_bounds__(256) void binA(const int* __restrict__ src,
                                            const int* __restrict__ dst,
                                            int* __restrict__ bucket_cur,
                                            uint2* __restrict__ binned) {
  __shared__ int hist[NBUK];
  __shared__ int sc[256];
  __shared__ int lbase[NBUK];
  __shared__ int gbase[NBUK];
  __shared__ int lcur[NBUK];
  __shared__ uint2 stage[EPB];
  int t = threadIdx.x;
  int e0 = blockIdx.x * EPB;
  if (t < NBUK) hist[t] = 0;
  __syncthreads();
  int es[8], ed[8];
#pragma unroll
  for (int j = 0; j < 8; ++j) {
    int e = e0 + t + j * 256;
    if (e < NE) {
      es[j] = src[e];
      ed[j] = dst[e];
      atomicAdd(&hist[ed[j] >> 9], 1);
    } else {
      es[j] = -1;
      ed[j] = 0;
    }
  }
  __syncthreads();
  sc[t] = (t < NBUK) ? hist[t] : 0;
  __syncthreads();
  for (int off = 1; off < 256; off <<= 1) {
    int v = (t >= off) ? sc[t - off] : 0;
    __syncthreads();
    sc[t] += v;
    __syncthreads();
  }
  if (t < NBUK) {
    int h = hist[t];
    int lb = sc[t] - h;
    lbase[t] = lb;
    lcur[t] = lb;
    if (h > 0) gbase[t] = atomicAdd(&bucket_cur[t], h);
  }
  __syncthreads();
#pragma unroll
  for (int j = 0; j < 8; ++j) {
    if (es[j] >= 0) {
      int b = ed[j] >> 9;
      int slot = atomicAdd(&lcur[b], 1);
      stage[slot] = make_uint2((unsigned)es[j], (unsigned)ed[j]);
    }
  }
  __syncthreads();
  int total = min(EPB, NE - e0);
  for (int i = t; i < total; i += 256) {
    uint2 p = stage[i];
    int b = (int)(p.y >> 9);
    binned[(size_t)gbase[b] + (i - lbase[b])] = p;
  }
}

// pass B: one block per bucket; order within bucket in LDS, write col coalesced
__global__ __launch_bounds__(256) void binB(const uint2* __restrict__ binned,
                                            const int* __restrict__ row_ptr,
                                            int* __restrict__ col) {
  __shared__ int cur[NPB];
  __shared__ int srcS[BCAP];
  int b = blockIdx.x;
  int n0 = b * NPB;
  int n1 = min(n0 + NPB, NN);
  int base = row_ptr[n0];
  int end = row_ptr[n1];
  int cnt = end - base;
  int t = threadIdx.x;
#pragma unroll
  for (int i = t; i < NPB; i += 256) {
    int n = n0 + i;
    cur[i] = (n < n1) ? (row_ptr[n] - base) : 0;
  }
  __syncthreads();
  for (int i = t; i < cnt; i += 256) {
    uint2 p = binned[(size_t)base + i];
    int slot = atomicAdd(&cur[(int)p.y - n0], 1);
    srcS[slot] = (int)p.x;
  }
  __syncthreads();
  for (int i = t; i < cnt; i += 256) col[(size_t)base + i] = srcS[i];
}

// ---------------- x -> fp16 shadow ----------------

__global__ __launch_bounds__(256) void tohalf(const float* __restrict__ x,
                                              __half* __restrict__ x16) {
  size_t o = ((size_t)blockIdx.x * 256 + threadIdx.x) * 8;
  float4 a = *(const float4*)(x + o);
  float4 b = *(const float4*)(x + o + 4);
  union { uint4 u; __half h[8]; } U;
  U.h[0] = __float2half(a.x); U.h[1] = __float2half(a.y);
  U.h[2] = __float2half(a.z); U.h[3] = __float2half(a.w);
  U.h[4] = __float2half(b.x); U.h[5] = __float2half(b.y);
  U.h[6] = __float2half(b.z); U.h[7] = __float2half(b.w);
  *(uint4*)(x16 + o) = U.u;
}

// ---------------- mean aggregation: wave/node, fp16 rows, shfl ids, MLP=8 ----------------

__global__ __launch_bounds__(256) void agg_kernel(const __half* __restrict__ h16,
                                                  const int* __restrict__ row_ptr,
                                                  const int* __restrict__ col,
                                                  const float* __restrict__ deg_inv,
                                                  float* __restrict__ agg) {
  int w = (int)((blockIdx.x * 256u + threadIdx.x) >> 6);
  int lane = threadIdx.x & 63;
  if (w >= NN) return;
  int beg = row_ptr[w], end = row_ptr[w + 1];
  float acc = 0.f;
  int e = beg;
  while (e < end) {
    int chunk = end - e;
    if (chunk > 64) chunk = 64;
    int cv = col[e + (lane < chunk ? lane : chunk - 1)];
    int i = 0;
    for (; i + 8 <= chunk; i += 8) {
      int s0 = __shfl(cv, i + 0, 64), s1 = __shfl(cv, i + 1, 64);
      int s2 = __shfl(cv, i + 2, 64), s3 = __shfl(cv, i + 3, 64);
      int s4 = __shfl(cv, i + 4, 64), s5 = __shfl(cv, i + 5, 64);
      int s6 = __shfl(cv, i + 6, 64), s7 = __shfl(cv, i + 7, 64);
      float v0 = __half2float(h16[(size_t)s0 * 64 + lane]);
      float v1 = __half2float(h16[(size_t)s1 * 64 + lane]);
      float v2 = __half2float(h16[(size_t)s2 * 64 + lane]);
      float v3 = __half2float(h16[(size_t)s3 * 64 + lane]);
      float v4 = __half2float(h16[(size_t)s4 * 64 + lane]);
      float v5 = __half2float(h16[(size_t)s5 * 64 + lane]);
      float v6 = __half2float(h16[(size_t)s6 * 64 + lane]);
      float v7 = __half2float(h16[(size_t)s7 * 64 + lane]);
      acc += ((v0 + v1) + (v2 + v3)) + ((v4 + v5) + (v6 + v7));
    }
    for (; i < chunk; ++i) {
      int s = __shfl(cv, i, 64);
      acc += __half2float(h16[(size_t)s * 64 + lane]);
    }
    e += chunk;
  }
  agg[(size_t)w * 64 + lane] = acc * deg_inv[w];
}

// ---------------- fused layer GEMM + projection ----------------
// hn = agg@Wl + bl + h@Wr ; out (+)= hn @ Wp (+ bp on layer 0)
// h read as fp16, hn stored as fp16; GEMM/proj accumulate fp32.
// flags bit0: first layer (init out with bp); bit1: write hn16.

#define LP 68  // padded leading dim

__global__ __launch_bounds__(256) void layer_proj(
    const float* __restrict__ agg, const __half* __restrict__ h16,
    const float* __restrict__ Wl, const float* __restrict__ bl,
    const float* __restrict__ Wr, const float* __restrict__ Wp,
    const float* __restrict__ bp,
    __half* __restrict__ hn16, float* __restrict__ out, int flags) {
  __shared__ float aS[64][LP];
  __shared__ float hS[64][LP];
  __shared__ float WlS[32 * 64];
  __shared__ float WrS[32 * 64];
  int tid = threadIdx.x;
  int base = blockIdx.x * 64;

  // stage agg tile (fp32): 1024 float4s, 4/thread
#pragma unroll
  for (int j = 0; j < 4; ++j) {
    int idx = tid + j * 256;
    int r = idx >> 4, c4 = (idx & 15) << 2;
    int node = base + r;
    float4 av = make_float4(0.f, 0.f, 0.f, 0.f);
    if (node < NN) av = *(const float4*)(agg + (size_t)node * 64 + c4);
    *(float4*)&aS[r][c4] = av;
  }
  // stage h tile (fp16 -> fp32): 512 uint4s (8 halves), 2/thread
#pragma unroll
  for (int j = 0; j < 2; ++j) {
    int idx = tid + j * 256;
    int r = idx >> 3, c8 = (idx & 7) << 3;
    int node = base + r;
    if (node < NN) {
      union { uint4 u; __half2 h2[4]; } U;
      U.u = *(const uint4*)(h16 + (size_t)node * 64 + c8);
#pragma unroll
      for (int q = 0; q < 4; ++q) {
        float2 f = __half22float2(U.h2[q]);
        hS[r][c8 + 2 * q] = f.x;
        hS[r][c8 + 2 * q + 1] = f.y;
      }
    } else {
#pragma unroll
      for (int q = 0; q < 8; ++q) hS[r][c8 + q] = 0.f;
    }
  }

  int tx = tid & 7, ty = tid >> 3;
  int m0 = ty * 2, c0 = tx * 8;
  float acc[2][8];
  {
    float4 b0 = *(const float4*)(bl + c0);
    float4 b1 = *(const float4*)(bl + c0 + 4);
#pragma unroll
    for (int m = 0; m < 2; ++m) {
      acc[m][0] = b0.x; acc[m][1] = b0.y; acc[m][2] = b0.z; acc[m][3] = b0.w;
      acc[m][4] = b1.x; acc[m][5] = b1.y; acc[m][6] = b1.z; acc[m][7] = b1.w;
    }
  }

  for (int p = 0; p < 2; ++p) {
    __syncthreads();  // p=0 fences tile staging; p=1 fences prior W reads
#pragma unroll
    for (int j = 0; j < 2; ++j) {
      int idx = tid + j * 256;
      ((float4*)WlS)[idx] = ((const float4*)(Wl + p * 2048))[idx];
      ((float4*)WrS)[idx] = ((const float4*)(Wr + p * 2048))[idx];
    }
    __syncthreads();
#pragma unroll 8
    for (int k = 0; k < 32; ++k) {
      int kg = p * 32 + k;
      float4 l0 = *(const float4*)&WlS[k * 64 + c0];
      float4 l1 = *(const float4*)&WlS[k * 64 + c0 + 4];
      float4 r0 = *(const float4*)&WrS[k * 64 + c0];
      float4 r1 = *(const float4*)&WrS[k * 64 + c0 + 4];
#pragma unroll
      for (int m = 0; m < 2; ++m) {
        float a = aS[m0 + m][kg];
        float hh = hS[m0 + m][kg];
        acc[m][0] += a * l0.x + hh * r0.x;
        acc[m][1] += a * l0.y + hh * r0.y;
        acc[m][2] += a * l0.z + hh * r0.z;
        acc[m][3] += a * l0.w + hh * r0.w;
        acc[m][4] += a * l1.x + hh * r1.x;
        acc[m][5] += a * l1.y + hh * r1.y;
        acc[m][6] += a * l1.z + hh * r1.z;
        acc[m][7] += a * l1.w + hh * r1.w;
      }
    }
  }

  // write hn16 (skipped on last layer)
  if (flags & 2) {
#pragma unroll
    for (int m = 0; m < 2; ++m) {
      int node = base + m0 + m;
      if (node < NN) {
        union { uint4 u; __half h[8]; } U;
#pragma unroll
        for (int q = 0; q < 8; ++q) U.h[q] = __float2half(acc[m][q]);
        *(uint4*)(hn16 + (size_t)node * 64 + c0) = U.u;
      }
    }
  }

  __syncthreads();  // all GEMM reads of aS done
  // stash fp32 hn tile into aS for the projection (full precision proj path)
#pragma unroll
  for (int m = 0; m < 2; ++m) {
    *(float4*)&aS[m0 + m][c0] =
        make_float4(acc[m][0], acc[m][1], acc[m][2], acc[m][3]);
    *(float4*)&aS[m0 + m][c0 + 4] =
        make_float4(acc[m][4], acc[m][5], acc[m][6], acc[m][7]);
  }
  __syncthreads();

  // projection: 4 threads per node, 8 cols each; Wp via L1 (8KB, hot)
  int nloc = tid >> 2;
  int pc0 = (tid & 3) * 8;
  int node = base + nloc;
  if (node < NN) {
    float pa[8];
    {
      const float* src = (flags & 1) ? (bp + pc0) : (out + (size_t)node * 32 + pc0);
      float4 p0 = *(const float4*)src;
      float4 p1 = *(const float4*)(src + 4);
      pa[0] = p0.x; pa[1] = p0.y; pa[2] = p0.z; pa[3] = p0.w;
      pa[4] = p1.x; pa[5] = p1.y; pa[6] = p1.z; pa[7] = p1.w;
    }
#pragma unroll 8
    for (int k = 0; k < 64; ++k) {
      float a = aS[nloc][k];
      float4 w0 = *(const float4*)(Wp + k * 32 + pc0);
      float4 w1 = *(const float4*)(Wp + k * 32 + pc0 + 4);
      pa[0] += a * w0.x; pa[1] += a * w0.y; pa[2] += a * w0.z; pa[3] += a * w0.w;
      pa[4] += a * w1.x; pa[5] += a * w1.y; pa[6] += a * w1.z; pa[7] += a * w1.w;
    }
    *(float4*)(out + (size_t)node * 32 + pc0) = make_float4(pa[0], pa[1], pa[2], pa[3]);
    *(float4*)(out + (size_t)node * 32 + pc0 + 4) = make_float4(pa[4], pa[5], pa[6], pa[7]);
  }
}

// ---------------- launch ----------------

extern "C" void kernel_launch(void* const* d_in, const int* in_sizes, int n_in,
                              void* d_out, int out_size, void* d_ws, size_t ws_size,
                              hipStream_t stream) {
  const float* x  = (const float*)d_in[0];
  const int*   ei = (const int*)d_in[1];   // [2, NE] int32
  const float* Wl = (const float*)d_in[2];
  const float* bl = (const float*)d_in[3];
  const float* Wr = (const float*)d_in[4];
  const float* Wp = (const float*)d_in[5];
  const float* bp = (const float*)d_in[6];
  float* out = (float*)d_out;

  char* ws = (char*)d_ws;
  size_t off = 0;
  auto alloc = [&](size_t bytes) {
    void* p = ws + off;
    off = (off + bytes + 255) & ~(size_t)255;
    return p;
  };
  int*    cnt        = (int*)alloc((size_t)NN * 4);
  int*    row_ptr    = (int*)alloc(((size_t)NN + 1) * 4);
  float*  deginv     = (float*)alloc((size_t)NN * 4);
  int*    col        = (int*)alloc((size_t)NE * 4);
  int*    tile_sum   = (int*)alloc((size_t)NTILES * 4);
  int*    tile_off   = (int*)alloc((size_t)NTILES * 4);
  int*    bucket_cur = (int*)alloc((size_t)NBUK * 4);
  uint2*  binned     = (uint2*)alloc((size_t)NE * 8);
  float*  agg        = (float*)alloc((size_t)NN * 64 * 4);
  __half* x16        = (__half*)alloc((size_t)NN * 64 * 2);
  __half* h16A       = (__half*)alloc((size_t)NN * 64 * 2);
  __half* h16B       = (__half*)alloc((size_t)NN * 64 * 2);

  hipMemsetAsync(cnt, 0, (size_t)NN * 4, stream);
  tohalf<<<3125, 256, 0, stream>>>(x, x16);          // NN*64/8/256 = 3125
  count_kernel<<<NE / 256, 256, 0, stream>>>(ei + NE, cnt);
  scan_reduce<<<NTILES, 256, 0, stream>>>(cnt, tile_sum);
  scan_tiles<<<1, 128, 0, stream>>>(tile_sum, tile_off, row_ptr);
  scan_apply<<<NTILES, 256, 0, stream>>>(cnt, tile_off, row_ptr, deginv);
  bcur_init<<<1, 256, 0, stream>>>(row_ptr, bucket_cur);
  binA<<<ABLK, 256, 0, stream>>>(ei, ei + NE, bucket_cur, binned);
  binB<<<NBUK, 256, 0, stream>>>(binned, row_ptr, col);

  const __half* cur16 = x16;
  __half* bufs[2] = {h16A, h16B};
  int nblk = (NN + 63) / 64;
  for (int l = 0; l < 4; ++l) {
    agg_kernel<<<(NN + 3) / 4, 256, 0, stream>>>(cur16, row_ptr, col, deginv, agg);
    __half* nxt = bufs[l & 1];
    int flags = (l == 0 ? 1 : 0) | (l < 3 ? 2 : 0);
    layer_proj<<<nblk, 256, 0, stream>>>(agg, cur16, Wl + l * 4096, bl + l * 64,
                                         Wr + l * 4096, Wp + l * 2048, bp,
                                         nxt, out, flags);
    cur16 = nxt;
  }
}

// Round 10
// 500.433 us; speedup vs baseline: 2.5663x; 1.3461x over previous
//
#include <hip/hip_runtime.h>
#include <hip/hip_fp16.h>

#define NN 100000
#define NE 1600000
#define NNP (NN + 64)  // row-padded feature buffers (last block reads past NN)

#define SCAN_TILE 1024
#define NTILES ((NN + SCAN_TILE - 1) / SCAN_TILE)  // 98

// CSR bucket sort params
#define NPB 512
#define NBUK ((NN + NPB - 1) / NPB)      // 196
#define EPB 2048
#define ABLK ((NE + EPB - 1) / EPB)      // 782
#define BCAP 10240

typedef _Float16 half8 __attribute__((ext_vector_type(8)));
typedef float f32x4 __attribute__((ext_vector_type(4)));

// ---------------- degree count + row_ptr scan ----------------

__global__ __launch_bounds__(256) void count_kernel(const int* __restrict__ dst,
                                                    int* __restrict__ cnt) {
  int e = blockIdx.x * 256 + threadIdx.x;
  atomicAdd(&cnt[dst[e]], 1);
}

__global__ __launch_bounds__(256) void scan_reduce(const int* __restrict__ cnt,
                                                   int* __restrict__ tile_sum) {
  __shared__ int ws[4];
  int t = threadIdx.x;
  int base = blockIdx.x * SCAN_TILE + t * 4;
  int s = 0;
#pragma unroll
  for (int i = 0; i < 4; ++i) {
    int idx = base + i;
    if (idx < NN) s += cnt[idx];
  }
#pragma unroll
  for (int off = 32; off; off >>= 1) s += __shfl_down(s, off, 64);
  if ((t & 63) == 0) ws[t >> 6] = s;
  __syncthreads();
  if (t == 0) tile_sum[blockIdx.x] = ws[0] + ws[1] + ws[2] + ws[3];
}

__global__ __launch_bounds__(128) void scan_tiles(const int* __restrict__ tile_sum,
                                                  int* __restrict__ tile_off,
                                                  int* __restrict__ row_ptr) {
  __shared__ int part[128];
  int t = threadIdx.x;
  int v = (t < NTILES) ? tile_sum[t] : 0;
  part[t] = v;
  __syncthreads();
  for (int off = 1; off < 128; off <<= 1) {
    int u = (t >= off) ? part[t - off] : 0;
    __syncthreads();
    part[t] += u;
    __syncthreads();
  }
  if (t < NTILES) tile_off[t] = part[t] - v;
  if (t == 127) row_ptr[NN] = part[127];
}

__global__ __launch_bounds__(256) void scan_apply(const int* __restrict__ cnt,
                                                  const int* __restrict__ tile_off,
                                                  int* __restrict__ row_ptr,
                                                  float* __restrict__ deg_inv) {
  __shared__ int part[256];
  int t = threadIdx.x;
  int base = blockIdx.x * SCAN_TILE + t * 4;
  int c[4];
#pragma unroll
  for (int i = 0; i < 4; ++i) {
    int idx = base + i;
    c[i] = (idx < NN) ? cnt[idx] : 0;
  }
  int s = c[0] + c[1] + c[2] + c[3];
  part[t] = s;
  __syncthreads();
  for (int off = 1; off < 256; off <<= 1) {
    int u = (t >= off) ? part[t - off] : 0;
    __syncthreads();
    part[t] += u;
    __syncthreads();
  }
  int run = tile_off[blockIdx.x] + part[t] - s;
#pragma unroll
  for (int i = 0; i < 4; ++i) {
    int idx = base + i;
    if (idx < NN) {
      row_ptr[idx] = run;
      deg_inv[idx] = 1.0f / (float)(c[i] > 1 ? c[i] : 1);
      run += c[i];
    }
  }
}

// ---------------- two-pass binned CSR fill ----------------

__global__ __launch_bounds__(256) void bcur_init(const int* __restrict__ row_ptr,
                                                 int* __restrict__ bucket_cur) {
  int t = blockIdx.x * 256 + threadIdx.x;
  if (t < NBUK) bucket_cur[t] = row_ptr[min(t * NPB, NN)];
}

__global__ __launch_bounds__(256) void binA(const int* __restrict__ src,
                                            const int* __restrict__ dst,
                                            int* __restrict__ bucket_cur,
                                            uint2* __restrict__ binned) {
  __shared__ int hist[NBUK];
  __shared__ int sc[256];
  __shared__ int lbase[NBUK];
  __shared__ int gbase[NBUK];
  __shared__ int lcur[NBUK];
  __shared__ uint2 stage[EPB];
  int t = threadIdx.x;
  int e0 = blockIdx.x * EPB;
  if (t < NBUK) hist[t] = 0;
  __syncthreads();
  int es[8], ed[8];
#pragma unroll
  for (int j = 0; j < 8; ++j) {
    int e = e0 + t + j * 256;
    if (e < NE) {
      es[j] = src[e];
      ed[j] = dst[e];
      atomicAdd(&hist[ed[j] >> 9], 1);
    } else {
      es[j] = -1;
      ed[j] = 0;
    }
  }
  __syncthreads();
  sc[t] = (t < NBUK) ? hist[t] : 0;
  __syncthreads();
  for (int off = 1; off < 256; off <<= 1) {
    int v = (t >= off) ? sc[t - off] : 0;
    __syncthreads();
    sc[t] += v;
    __syncthreads();
  }
  if (t < NBUK) {
    int h = hist[t];
    int lb = sc[t] - h;
    lbase[t] = lb;
    lcur[t] = lb;
    if (h > 0) gbase[t] = atomicAdd(&bucket_cur[t], h);
  }
  __syncthreads();
#pragma unroll
  for (int j = 0; j < 8; ++j) {
    if (es[j] >= 0) {
      int b = ed[j] >> 9;
      int slot = atomicAdd(&lcur[b], 1);
      stage[slot] = make_uint2((unsigned)es[j], (unsigned)ed[j]);
    }
  }
  __syncthreads();
  int total = min(EPB, NE - e0);
  for (int i = t; i < total; i += 256) {
    uint2 p = stage[i];
    int b = (int)(p.y >> 9);
    binned[(size_t)gbase[b] + (i - lbase[b])] = p;
  }
}

__global__ __launch_bounds__(256) void binB(const uint2* __restrict__ binned,
                                            const int* __restrict__ row_ptr,
                                            int* __restrict__ col) {
  __shared__ int cur[NPB];
  __shared__ int srcS[BCAP];
  int b = blockIdx.x;
  int n0 = b * NPB;
  int n1 = min(n0 + NPB, NN);
  int base = row_ptr[n0];
  int end = row_ptr[n1];
  int cnt = end - base;
  int t = threadIdx.x;
  for (int i = t; i < NPB; i += 256) {
    int n = n0 + i;
    cur[i] = (n < n1) ? (row_ptr[n] - base) : 0;
  }
  __syncthreads();
  for (int i = t; i < cnt; i += 256) {
    uint2 p = binned[(size_t)base + i];
    int slot = atomicAdd(&cur[(int)p.y - n0], 1);
    srcS[slot] = (int)p.x;
  }
  __syncthreads();
  for (int i = t; i < cnt; i += 256) col[(size_t)base + i] = srcS[i];
}

// ---------------- x -> fp16 shadow ----------------

__global__ __launch_bounds__(256) void tohalf(const float* __restrict__ x,
                                              __half* __restrict__ x16) {
  size_t o = ((size_t)blockIdx.x * 256 + threadIdx.x) * 8;
  float4 a = *(const float4*)(x + o);
  float4 b = *(const float4*)(x + o + 4);
  union { uint4 u; __half h[8]; } U;
  U.h[0] = __float2half(a.x); U.h[1] = __float2half(a.y);
  U.h[2] = __float2half(a.z); U.h[3] = __float2half(a.w);
  U.h[4] = __float2half(b.x); U.h[5] = __float2half(b.y);
  U.h[6] = __float2half(b.z); U.h[7] = __float2half(b.w);
  *(uint4*)(x16 + o) = U.u;
}

// ---------------- weight prep: fp16 transposed B operands ----------------
// WcatT: [L][64 cols][128 k] with k<64 -> Wl[k][j], k>=64 -> Wr[k-64][j]
// WpT:   [L][32 cols][64 k]  = Wp[(l*64+k)][j]

__global__ __launch_bounds__(256) void prep_weights(const float* __restrict__ Wl,
                                                    const float* __restrict__ Wr,
                                                    const float* __restrict__ Wp,
                                                    _Float16* __restrict__ WcatT,
                                                    _Float16* __restrict__ WpT) {
  int t = blockIdx.x * 256 + threadIdx.x;
  if (t < 4 * 64 * 128) {
    int l = t >> 13, rem = t & 8191, j = rem >> 7, k = rem & 127;
    float v = (k < 64) ? Wl[l * 4096 + k * 64 + j] : Wr[l * 4096 + (k - 64) * 64 + j];
    WcatT[t] = (_Float16)v;
  }
  if (t < 4 * 32 * 64) {
    int l = t >> 11, rem = t & 2047, j = rem >> 6, k = rem & 63;
    WpT[t] = (_Float16)Wp[(size_t)(l * 64 + k) * 32 + j];
  }
}

// ---------------- mean aggregation: wave/node, fp16 rows, shfl ids, MLP=8 ----------------

__global__ __launch_bounds__(256) void agg_kernel(const __half* __restrict__ h16,
                                                  const int* __restrict__ row_ptr,
                                                  const int* __restrict__ col,
                                                  const float* __restrict__ deg_inv,
                                                  __half* __restrict__ agg16) {
  int w = (int)((blockIdx.x * 256u + threadIdx.x) >> 6);
  int lane = threadIdx.x & 63;
  if (w >= NN) return;
  int beg = row_ptr[w], end = row_ptr[w + 1];
  float acc = 0.f;
  int e = beg;
  while (e < end) {
    int chunk = end - e;
    if (chunk > 64) chunk = 64;
    int cv = col[e + (lane < chunk ? lane : chunk - 1)];
    int i = 0;
    for (; i + 8 <= chunk; i += 8) {
      int s0 = __shfl(cv, i + 0, 64), s1 = __shfl(cv, i + 1, 64);
      int s2 = __shfl(cv, i + 2, 64), s3 = __shfl(cv, i + 3, 64);
      int s4 = __shfl(cv, i + 4, 64), s5 = __shfl(cv, i + 5, 64);
      int s6 = __shfl(cv, i + 6, 64), s7 = __shfl(cv, i + 7, 64);
      float v0 = __half2float(h16[(size_t)s0 * 64 + lane]);
      float v1 = __half2float(h16[(size_t)s1 * 64 + lane]);
      float v2 = __half2float(h16[(size_t)s2 * 64 + lane]);
      float v3 = __half2float(h16[(size_t)s3 * 64 + lane]);
      float v4 = __half2float(h16[(size_t)s4 * 64 + lane]);
      float v5 = __half2float(h16[(size_t)s5 * 64 + lane]);
      float v6 = __half2float(h16[(size_t)s6 * 64 + lane]);
      float v7 = __half2float(h16[(size_t)s7 * 64 + lane]);
      acc += ((v0 + v1) + (v2 + v3)) + ((v4 + v5) + (v6 + v7));
    }
    for (; i < chunk; ++i) {
      int s = __shfl(cv, i, 64);
      acc += __half2float(h16[(size_t)s * 64 + lane]);
    }
    e += chunk;
  }
  agg16[(size_t)w * 64 + lane] = __float2half(acc * deg_inv[w]);
}

// ---------------- MFMA layer: hn = [agg|h] @ [Wl;Wr] + bl ; out (+)= hn @ Wp ----------------
// 64 nodes / 256-thread block (4 waves; wave w owns rows w*16..w*16+15).
// mfma_f32_16x16x32_f16 layouts (m89/m91-verified family):
//   A: row=lane&15, k=(lane>>4)*8+i   B: col=lane&15, k=(lane>>4)*8+i
//   D: col=lane&15, row=(lane>>4)*4+reg
// flags bit0: first layer (init out with bp); bit1: write hn16.

#define PADC 72  // cS row stride in halves: 144B rows keep half8 reads 16B-aligned

__global__ __launch_bounds__(256) void layer_mfma(
    const _Float16* __restrict__ agg16, const _Float16* __restrict__ h16,
    const _Float16* __restrict__ WcatT, const float* __restrict__ bl,
    const _Float16* __restrict__ WpT, const float* __restrict__ bp,
    _Float16* __restrict__ hn16, float* __restrict__ out, int flags) {
  __shared__ _Float16 cS[64 * PADC];
  int tid = threadIdx.x;
  int w = tid >> 6, l = tid & 63;
  int lr = l & 15, lg = l >> 4;
  int base = blockIdx.x * 64;
  int arow = base + (w << 4) + lr;  // A-operand row (node); padded buffers cover OOB

  // ---- main GEMM: 4 col-tiles x (2 agg + 2 h) K-steps ----
  f32x4 acc[4];
#pragma unroll
  for (int ct = 0; ct < 4; ++ct) {
    float b = bl[ct * 16 + lr];
    acc[ct] = (f32x4){b, b, b, b};
  }
  const half8 a0 = *(const half8*)(agg16 + (size_t)arow * 64 + lg * 8);
  const half8 a1 = *(const half8*)(agg16 + (size_t)arow * 64 + 32 + lg * 8);
  const half8 a2 = *(const half8*)(h16 + (size_t)arow * 64 + lg * 8);
  const half8 a3 = *(const half8*)(h16 + (size_t)arow * 64 + 32 + lg * 8);
#pragma unroll
  for (int ct = 0; ct < 4; ++ct) {
    const _Float16* wb = WcatT + (ct * 16 + lr) * 128 + lg * 8;
    half8 b0 = *(const half8*)(wb);
    half8 b1 = *(const half8*)(wb + 32);
    half8 b2 = *(const half8*)(wb + 64);
    half8 b3 = *(const half8*)(wb + 96);
    acc[ct] = __builtin_amdgcn_mfma_f32_16x16x32_f16(a0, b0, acc[ct], 0, 0, 0);
    acc[ct] = __builtin_amdgcn_mfma_f32_16x16x32_f16(a1, b1, acc[ct], 0, 0, 0);
    acc[ct] = __builtin_amdgcn_mfma_f32_16x16x32_f16(a2, b2, acc[ct], 0, 0, 0);
    acc[ct] = __builtin_amdgcn_mfma_f32_16x16x32_f16(a3, b3, acc[ct], 0, 0, 0);
  }

  // ---- stage hn tile to LDS (fp16): D-layout scatter ----
#pragma unroll
  for (int ct = 0; ct < 4; ++ct)
#pragma unroll
    for (int r = 0; r < 4; ++r)
      cS[((w << 4) + (lg << 2) + r) * PADC + ct * 16 + lr] = (_Float16)acc[ct][r];
  __syncthreads();

  // ---- coalesced hn16 write from LDS (skipped on last layer) ----
  if (flags & 2) {
#pragma unroll
    for (int j = 0; j < 2; ++j) {
      int idx = tid + j * 256;        // 0..511 half8 chunks
      int row = idx >> 3, c8 = (idx & 7) * 8;
      *(half8*)(hn16 + (size_t)(base + row) * 64 + c8) =
          *(const half8*)(cS + row * PADC + c8);
    }
  }

  // ---- projection: out(64x32) (+)= C(64x64) @ Wp(64x32) ----
  f32x4 pacc[2];
#pragma unroll
  for (int pt = 0; pt < 2; ++pt) {
    int colo = pt * 16 + lr;
    if (flags & 1) {
      float b = bp[colo];
      pacc[pt] = (f32x4){b, b, b, b};
    } else {
#pragma unroll
      for (int r = 0; r < 4; ++r) {
        int row = base + (w << 4) + (lg << 2) + r;
        pacc[pt][r] = (row < NN) ? out[(size_t)row * 32 + colo] : 0.f;
      }
    }
  }
  const _Float16* crow = cS + ((w << 4) + lr) * PADC + lg * 8;
  half8 c0 = *(const half8*)(crow);
  half8 c1 = *(const half8*)(crow + 32);
#pragma unroll
  for (int pt = 0; pt < 2; ++pt) {
    const _Float16* wp = WpT + (pt * 16 + lr) * 64 + lg * 8;
    half8 w0 = *(const half8*)(wp);
    half8 w1 = *(const half8*)(wp + 32);
    pacc[pt] = __builtin_amdgcn_mfma_f32_16x16x32_f16(c0, w0, pacc[pt], 0, 0, 0);
    pacc[pt] = __builtin_amdgcn_mfma_f32_16x16x32_f16(c1, w1, pacc[pt], 0, 0, 0);
  }
#pragma unroll
  for (int pt = 0; pt < 2; ++pt) {
    int colo = pt * 16 + lr;
#pragma unroll
    for (int r = 0; r < 4; ++r) {
      int row = base + (w << 4) + (lg << 2) + r;
      if (row < NN) out[(size_t)row * 32 + colo] = pacc[pt][r];
    }
  }
}

// ---------------- launch ----------------

extern "C" void kernel_launch(void* const* d_in, const int* in_sizes, int n_in,
                              void* d_out, int out_size, void* d_ws, size_t ws_size,
                              hipStream_t stream) {
  const float* x  = (const float*)d_in[0];
  const int*   ei = (const int*)d_in[1];   // [2, NE] int32
  const float* Wl = (const float*)d_in[2];
  const float* bl = (const float*)d_in[3];
  const float* Wr = (const float*)d_in[4];
  const float* Wp = (const float*)d_in[5];
  const float* bp = (const float*)d_in[6];
  float* out = (float*)d_out;

  char* ws = (char*)d_ws;
  size_t off = 0;
  auto alloc = [&](size_t bytes) {
    void* p = ws + off;
    off = (off + bytes + 255) & ~(size_t)255;
    return p;
  };
  int*      cnt        = (int*)alloc((size_t)NN * 4);
  int*      row_ptr    = (int*)alloc(((size_t)NN + 1) * 4);
  float*    deginv     = (float*)alloc((size_t)NN * 4);
  int*      col        = (int*)alloc((size_t)NE * 4);
  int*      tile_sum   = (int*)alloc((size_t)NTILES * 4);
  int*      tile_off   = (int*)alloc((size_t)NTILES * 4);
  int*      bucket_cur = (int*)alloc((size_t)NBUK * 4);
  uint2*    binned     = (uint2*)alloc((size_t)NE * 8);
  __half*   agg16      = (__half*)alloc((size_t)NNP * 64 * 2);
  __half*   x16        = (__half*)alloc((size_t)NNP * 64 * 2);
  __half*   h16A       = (__half*)alloc((size_t)NNP * 64 * 2);
  __half*   h16B       = (__half*)alloc((size_t)NNP * 64 * 2);
  _Float16* WcatT      = (_Float16*)alloc((size_t)4 * 64 * 128 * 2);
  _Float16* WpT        = (_Float16*)alloc((size_t)4 * 32 * 64 * 2);

  hipMemsetAsync(cnt, 0, (size_t)NN * 4, stream);
  tohalf<<<3125, 256, 0, stream>>>(x, x16);  // NN*64/8/256 = 3125 exact
  prep_weights<<<128, 256, 0, stream>>>(Wl, Wr, Wp, WcatT, WpT);
  count_kernel<<<NE / 256, 256, 0, stream>>>(ei + NE, cnt);
  scan_reduce<<<NTILES, 256, 0, stream>>>(cnt, tile_sum);
  scan_tiles<<<1, 128, 0, stream>>>(tile_sum, tile_off, row_ptr);
  scan_apply<<<NTILES, 256, 0, stream>>>(cnt, tile_off, row_ptr, deginv);
  bcur_init<<<1, 256, 0, stream>>>(row_ptr, bucket_cur);
  binA<<<ABLK, 256, 0, stream>>>(ei, ei + NE, bucket_cur, binned);
  binB<<<NBUK, 256, 0, stream>>>(binned, row_ptr, col);

  const __half* cur16 = x16;
  __half* bufs[2] = {h16A, h16B};
  int nblk = (NN + 63) / 64;  // 1563
  for (int l = 0; l < 4; ++l) {
    agg_kernel<<<(NN + 3) / 4, 256, 0, stream>>>(cur16, row_ptr, col, deginv, agg16);
    __half* nxt = bufs[l & 1];
    int flags = (l == 0 ? 1 : 0) | (l < 3 ? 2 : 0);
    layer_mfma<<<nblk, 256, 0, stream>>>(
        (const _Float16*)agg16, (const _Float16*)cur16,
        WcatT + l * 8192, bl + l * 64, WpT + l * 2048, bp,
        (_Float16*)nxt, out, flags);
    cur16 = nxt;
  }
}

// Round 11
// 433.308 us; speedup vs baseline: 2.9638x; 1.1549x over previous
//
#include <hip/hip_runtime.h>
#include <hip/hip_fp16.h>

#define NN 100000
#define NE 1600000
#define NNP (NN + 64)  // row-padded feature buffers (last block reads past NN)

// CSR bucket sort params
#define NPB 512                          // nodes per bucket (bucket = dst>>9)
#define NBUK ((NN + NPB - 1) / NPB)      // 196
#define EPB 2048                         // edges per binA block
#define ABLK ((NE + EPB - 1) / EPB)      // 782
#define BCAP 10240                       // segment capacity (mean 8192, sd ~90)

typedef _Float16 half8 __attribute__((ext_vector_type(8)));
typedef float f32x4 __attribute__((ext_vector_type(4)));

// ---------------- bucketed CSR build (no node-grained global atomics) ----------------

__global__ __launch_bounds__(256) void bucket_init(int* __restrict__ bucket_cur) {
  int t = blockIdx.x * 256 + threadIdx.x;
  if (t < NBUK) bucket_cur[t] = t * BCAP;
}

// pass A: bin (src,dst) pairs by dst>>9 into fixed-capacity segments
__global__ __launch_bounds__(256) void binA(const int* __restrict__ src,
                                            const int* __restrict__ dst,
                                            int* __restrict__ bucket_cur,
                                            uint2* __restrict__ binned) {
  __shared__ int hist[NBUK];
  __shared__ int sc[256];
  __shared__ int lbase[NBUK];
  __shared__ int gbase[NBUK];
  __shared__ int lcur[NBUK];
  __shared__ uint2 stage[EPB];
  int t = threadIdx.x;
  int e0 = blockIdx.x * EPB;
  if (t < NBUK) hist[t] = 0;
  __syncthreads();
  int es[8], ed[8];
#pragma unroll
  for (int j = 0; j < 8; ++j) {
    int e = e0 + t + j * 256;
    if (e < NE) {
      es[j] = src[e];
      ed[j] = dst[e];
      atomicAdd(&hist[ed[j] >> 9], 1);
    } else {
      es[j] = -1;
      ed[j] = 0;
    }
  }
  __syncthreads();
  sc[t] = (t < NBUK) ? hist[t] : 0;
  __syncthreads();
  for (int off = 1; off < 256; off <<= 1) {
    int v = (t >= off) ? sc[t - off] : 0;
    __syncthreads();
    sc[t] += v;
    __syncthreads();
  }
  if (t < NBUK) {
    int h = hist[t];
    int lb = sc[t] - h;
    lbase[t] = lb;
    lcur[t] = lb;
    if (h > 0) gbase[t] = atomicAdd(&bucket_cur[t], h);
  }
  __syncthreads();
#pragma unroll
  for (int j = 0; j < 8; ++j) {
    if (es[j] >= 0) {
      int b = ed[j] >> 9;
      int slot = atomicAdd(&lcur[b], 1);
      stage[slot] = make_uint2((unsigned)es[j], (unsigned)ed[j]);
    }
  }
  __syncthreads();
  int total = min(EPB, NE - e0);
  for (int i = t; i < total; i += 256) {
    uint2 p = stage[i];
    int b = (int)(p.y >> 9);
    binned[(size_t)gbase[b] + (i - lbase[b])] = p;
  }
}

// scan bucket fill counts -> global bucket bases
__global__ __launch_bounds__(256) void bucket_scan(const int* __restrict__ bucket_cur,
                                                   int* __restrict__ bucket_base,
                                                   int* __restrict__ row_ptr) {
  __shared__ int part[256];
  int t = threadIdx.x;
  int v = (t < NBUK) ? (bucket_cur[t] - t * BCAP) : 0;
  part[t] = v;
  __syncthreads();
  for (int off = 1; off < 256; off <<= 1) {
    int u = (t >= off) ? part[t - off] : 0;
    __syncthreads();
    part[t] += u;
    __syncthreads();
  }
  if (t < NBUK) bucket_base[t] = part[t] - v;
  if (t == 0) row_ptr[NN] = NE;
}

// pass B: per bucket — per-node histogram + scan in LDS, then write
// row_ptr / deg_inv / col all coalesced.
__global__ __launch_bounds__(256) void binB(const uint2* __restrict__ binned,
                                            const int* __restrict__ bucket_cur,
                                            const int* __restrict__ bucket_base,
                                            int* __restrict__ row_ptr,
                                            float* __restrict__ deg_inv,
                                            int* __restrict__ col) {
  __shared__ int hist[NPB];
  __shared__ int cur2[NPB];
  __shared__ int part[256];
  __shared__ int srcS[BCAP];
  int b = blockIdx.x;
  int n0 = b * NPB;
  int n1 = min(n0 + NPB, NN);
  int cnt = bucket_cur[b] - b * BCAP;
  int gb = bucket_base[b];
  size_t seg = (size_t)b * BCAP;
  int t = threadIdx.x;
  hist[t] = 0;
  hist[t + 256] = 0;
  __syncthreads();
  for (int i = t; i < cnt; i += 256)
    atomicAdd(&hist[(int)binned[seg + i].y - n0], 1);
  __syncthreads();
  int c0 = hist[2 * t], c1 = hist[2 * t + 1];
  int s = c0 + c1;
  part[t] = s;
  __syncthreads();
  for (int off = 1; off < 256; off <<= 1) {
    int u = (t >= off) ? part[t - off] : 0;
    __syncthreads();
    part[t] += u;
    __syncthreads();
  }
  int excl = part[t] - s;
  cur2[2 * t] = excl;
  cur2[2 * t + 1] = excl + c0;
  int n = n0 + 2 * t;
  if (n < n1) {
    row_ptr[n] = gb + excl;
    deg_inv[n] = 1.0f / (float)(c0 > 1 ? c0 : 1);
  }
  if (n + 1 < n1) {
    row_ptr[n + 1] = gb + excl + c0;
    deg_inv[n + 1] = 1.0f / (float)(c1 > 1 ? c1 : 1);
  }
  __syncthreads();
  for (int i = t; i < cnt; i += 256) {
    uint2 p = binned[seg + i];
    int slot = atomicAdd(&cur2[(int)p.y - n0], 1);
    srcS[slot] = (int)p.x;
  }
  __syncthreads();
  for (int i = t; i < cnt; i += 256) col[(size_t)gb + i] = srcS[i];
}

// ---------------- x -> fp16 shadow ----------------

__global__ __launch_bounds__(256) void tohalf(const float* __restrict__ x,
                                              __half* __restrict__ x16) {
  size_t o = ((size_t)blockIdx.x * 256 + threadIdx.x) * 8;
  float4 a = *(const float4*)(x + o);
  float4 b = *(const float4*)(x + o + 4);
  union { uint4 u; __half h[8]; } U;
  U.h[0] = __float2half(a.x); U.h[1] = __float2half(a.y);
  U.h[2] = __float2half(a.z); U.h[3] = __float2half(a.w);
  U.h[4] = __float2half(b.x); U.h[5] = __float2half(b.y);
  U.h[6] = __float2half(b.z); U.h[7] = __float2half(b.w);
  *(uint4*)(x16 + o) = U.u;
}

// ---------------- weight prep: fp16 transposed B operands ----------------

__global__ __launch_bounds__(256) void prep_weights(const float* __restrict__ Wl,
                                                    const float* __restrict__ Wr,
                                                    const float* __restrict__ Wp,
                                                    _Float16* __restrict__ WcatT,
                                                    _Float16* __restrict__ WpT) {
  int t = blockIdx.x * 256 + threadIdx.x;
  if (t < 4 * 64 * 128) {
    int l = t >> 13, rem = t & 8191, j = rem >> 7, k = rem & 127;
    float v = (k < 64) ? Wl[l * 4096 + k * 64 + j] : Wr[l * 4096 + (k - 64) * 64 + j];
    WcatT[t] = (_Float16)v;
  }
  if (t < 4 * 32 * 64) {
    int l = t >> 11, rem = t & 2047, j = rem >> 6, k = rem & 63;
    WpT[t] = (_Float16)Wp[(size_t)(l * 64 + k) * 32 + j];
  }
}

// ---------------- mean aggregation: wave/node, fp16 rows, shfl ids, MLP=8 ----------------

__global__ __launch_bounds__(256) void agg_kernel(const __half* __restrict__ h16,
                                                  const int* __restrict__ row_ptr,
                                                  const int* __restrict__ col,
                                                  const float* __restrict__ deg_inv,
                                                  __half* __restrict__ agg16) {
  int w = (int)((blockIdx.x * 256u + threadIdx.x) >> 6);
  int lane = threadIdx.x & 63;
  if (w >= NN) return;
  int beg = row_ptr[w], end = row_ptr[w + 1];
  float acc = 0.f;
  int e = beg;
  while (e < end) {
    int chunk = end - e;
    if (chunk > 64) chunk = 64;
    int cv = col[e + (lane < chunk ? lane : chunk - 1)];
    int i = 0;
    for (; i + 8 <= chunk; i += 8) {
      int s0 = __shfl(cv, i + 0, 64), s1 = __shfl(cv, i + 1, 64);
      int s2 = __shfl(cv, i + 2, 64), s3 = __shfl(cv, i + 3, 64);
      int s4 = __shfl(cv, i + 4, 64), s5 = __shfl(cv, i + 5, 64);
      int s6 = __shfl(cv, i + 6, 64), s7 = __shfl(cv, i + 7, 64);
      float v0 = __half2float(h16[(size_t)s0 * 64 + lane]);
      float v1 = __half2float(h16[(size_t)s1 * 64 + lane]);
      float v2 = __half2float(h16[(size_t)s2 * 64 + lane]);
      float v3 = __half2float(h16[(size_t)s3 * 64 + lane]);
      float v4 = __half2float(h16[(size_t)s4 * 64 + lane]);
      float v5 = __half2float(h16[(size_t)s5 * 64 + lane]);
      float v6 = __half2float(h16[(size_t)s6 * 64 + lane]);
      float v7 = __half2float(h16[(size_t)s7 * 64 + lane]);
      acc += ((v0 + v1) + (v2 + v3)) + ((v4 + v5) + (v6 + v7));
    }
    for (; i < chunk; ++i) {
      int s = __shfl(cv, i, 64);
      acc += __half2float(h16[(size_t)s * 64 + lane]);
    }
    e += chunk;
  }
  agg16[(size_t)w * 64 + lane] = __float2half(acc * deg_inv[w]);
}

// ---------------- MFMA layer: hn = [agg|h] @ [Wl;Wr] + bl ; out (+)= hn @ Wp ----------------
// 64 nodes / 256-thread block (4 waves; wave w owns rows w*16..w*16+15).
// mfma_f32_16x16x32_f16: A row=lane&15, k=(lane>>4)*8+i ; B col=lane&15 same k ;
// D col=lane&15, row=(lane>>4)*4+reg.  flags bit0: layer0; bit1: write hn16.

#define PADC 72

__global__ __launch_bounds__(256) void layer_mfma(
    const _Float16* __restrict__ agg16, const _Float16* __restrict__ h16,
    const _Float16* __restrict__ WcatT, const float* __restrict__ bl,
    const _Float16* __restrict__ WpT, const float* __restrict__ bp,
    _Float16* __restrict__ hn16, float* __restrict__ out, int flags) {
  __shared__ _Float16 cS[64 * PADC];
  int tid = threadIdx.x;
  int w = tid >> 6, l = tid & 63;
  int lr = l & 15, lg = l >> 4;
  int base = blockIdx.x * 64;
  int arow = base + (w << 4) + lr;

  f32x4 acc[4];
#pragma unroll
  for (int ct = 0; ct < 4; ++ct) {
    float b = bl[ct * 16 + lr];
    acc[ct] = (f32x4){b, b, b, b};
  }
  const half8 a0 = *(const half8*)(agg16 + (size_t)arow * 64 + lg * 8);
  const half8 a1 = *(const half8*)(agg16 + (size_t)arow * 64 + 32 + lg * 8);
  const half8 a2 = *(const half8*)(h16 + (size_t)arow * 64 + lg * 8);
  const half8 a3 = *(const half8*)(h16 + (size_t)arow * 64 + 32 + lg * 8);
#pragma unroll
  for (int ct = 0; ct < 4; ++ct) {
    const _Float16* wb = WcatT + (ct * 16 + lr) * 128 + lg * 8;
    half8 b0 = *(const half8*)(wb);
    half8 b1 = *(const half8*)(wb + 32);
    half8 b2 = *(const half8*)(wb + 64);
    half8 b3 = *(const half8*)(wb + 96);
    acc[ct] = __builtin_amdgcn_mfma_f32_16x16x32_f16(a0, b0, acc[ct], 0, 0, 0);
    acc[ct] = __builtin_amdgcn_mfma_f32_16x16x32_f16(a1, b1, acc[ct], 0, 0, 0);
    acc[ct] = __builtin_amdgcn_mfma_f32_16x16x32_f16(a2, b2, acc[ct], 0, 0, 0);
    acc[ct] = __builtin_amdgcn_mfma_f32_16x16x32_f16(a3, b3, acc[ct], 0, 0, 0);
  }

#pragma unroll
  for (int ct = 0; ct < 4; ++ct)
#pragma unroll
    for (int r = 0; r < 4; ++r)
      cS[((w << 4) + (lg << 2) + r) * PADC + ct * 16 + lr] = (_Float16)acc[ct][r];
  __syncthreads();

  if (flags & 2) {
#pragma unroll
    for (int j = 0; j < 2; ++j) {
      int idx = tid + j * 256;
      int row = idx >> 3, c8 = (idx & 7) * 8;
      *(half8*)(hn16 + (size_t)(base + row) * 64 + c8) =
          *(const half8*)(cS + row * PADC + c8);
    }
  }

  f32x4 pacc[2];
#pragma unroll
  for (int pt = 0; pt < 2; ++pt) {
    int colo = pt * 16 + lr;
    if (flags & 1) {
      float b = bp[colo];
      pacc[pt] = (f32x4){b, b, b, b};
    } else {
#pragma unroll
      for (int r = 0; r < 4; ++r) {
        int row = base + (w << 4) + (lg << 2) + r;
        pacc[pt][r] = (row < NN) ? out[(size_t)row * 32 + colo] : 0.f;
      }
    }
  }
  const _Float16* crow = cS + ((w << 4) + lr) * PADC + lg * 8;
  half8 c0 = *(const half8*)(crow);
  half8 c1 = *(const half8*)(crow + 32);
#pragma unroll
  for (int pt = 0; pt < 2; ++pt) {
    const _Float16* wp = WpT + (pt * 16 + lr) * 64 + lg * 8;
    half8 w0 = *(const half8*)(wp);
    half8 w1 = *(const half8*)(wp + 32);
    pacc[pt] = __builtin_amdgcn_mfma_f32_16x16x32_f16(c0, w0, pacc[pt], 0, 0, 0);
    pacc[pt] = __builtin_amdgcn_mfma_f32_16x16x32_f16(c1, w1, pacc[pt], 0, 0, 0);
  }
#pragma unroll
  for (int pt = 0; pt < 2; ++pt) {
    int colo = pt * 16 + lr;
#pragma unroll
    for (int r = 0; r < 4; ++r) {
      int row = base + (w << 4) + (lg << 2) + r;
      if (row < NN) out[(size_t)row * 32 + colo] = pacc[pt][r];
    }
  }
}

// ---------------- launch ----------------

extern "C" void kernel_launch(void* const* d_in, const int* in_sizes, int n_in,
                              void* d_out, int out_size, void* d_ws, size_t ws_size,
                              hipStream_t stream) {
  const float* x  = (const float*)d_in[0];
  const int*   ei = (const int*)d_in[1];   // [2, NE] int32
  const float* Wl = (const float*)d_in[2];
  const float* bl = (const float*)d_in[3];
  const float* Wr = (const float*)d_in[4];
  const float* Wp = (const float*)d_in[5];
  const float* bp = (const float*)d_in[6];
  float* out = (float*)d_out;

  char* ws = (char*)d_ws;
  size_t off = 0;
  auto alloc = [&](size_t bytes) {
    void* p = ws + off;
    off = (off + bytes + 255) & ~(size_t)255;
    return p;
  };
  int*      row_ptr     = (int*)alloc(((size_t)NN + 1) * 4);
  float*    deginv      = (float*)alloc((size_t)NN * 4);
  int*      col         = (int*)alloc((size_t)NE * 4);
  int*      bucket_cur  = (int*)alloc((size_t)NBUK * 4);
  int*      bucket_base = (int*)alloc((size_t)NBUK * 4);
  uint2*    binned      = (uint2*)alloc((size_t)NBUK * BCAP * 8);
  __half*   agg16       = (__half*)alloc((size_t)NNP * 64 * 2);
  __half*   x16         = (__half*)alloc((size_t)NNP * 64 * 2);
  __half*   h16A        = (__half*)alloc((size_t)NNP * 64 * 2);
  __half*   h16B        = (__half*)alloc((size_t)NNP * 64 * 2);
  _Float16* WcatT       = (_Float16*)alloc((size_t)4 * 64 * 128 * 2);
  _Float16* WpT         = (_Float16*)alloc((size_t)4 * 32 * 64 * 2);

  tohalf<<<3125, 256, 0, stream>>>(x, x16);
  prep_weights<<<128, 256, 0, stream>>>(Wl, Wr, Wp, WcatT, WpT);
  bucket_init<<<1, 256, 0, stream>>>(bucket_cur);
  binA<<<ABLK, 256, 0, stream>>>(ei, ei + NE, bucket_cur, binned);
  bucket_scan<<<1, 256, 0, stream>>>(bucket_cur, bucket_base, row_ptr);
  binB<<<NBUK, 256, 0, stream>>>(binned, bucket_cur, bucket_base, row_ptr, deginv, col);

  const __half* cur16 = x16;
  __half* bufs[2] = {h16A, h16B};
  int nblk = (NN + 63) / 64;
  for (int l = 0; l < 4; ++l) {
    agg_kernel<<<(NN + 3) / 4, 256, 0, stream>>>(cur16, row_ptr, col, deginv, agg16);
    __half* nxt = bufs[l & 1];
    int flags = (l == 0 ? 1 : 0) | (l < 3 ? 2 : 0);
    layer_mfma<<<nblk, 256, 0, stream>>>(
        (const _Float16*)agg16, (const _Float16*)cur16,
        WcatT + l * 8192, bl + l * 64, WpT + l * 2048, bp,
        (_Float16*)nxt, out, flags);
    cur16 = nxt;
  }
}

// Round 12
// 419.175 us; speedup vs baseline: 3.0638x; 1.0337x over previous
//
#include <hip/hip_runtime.h>
#include <hip/hip_fp16.h>

#define NN 100000
#define NE 1600000
#define NNP (NN + 64)  // row-padded feature buffers (last block reads past NN)

// CSR bucket sort params
#define NPB 512                          // nodes per bucket (bucket = dst>>9)
#define NBUK ((NN + NPB - 1) / NPB)      // 196
#define EPB 2048                         // edges per binA block
#define ABLK ((NE + EPB - 1) / EPB)      // 782
#define BCAP 10240                       // segment capacity (mean 8192, sd ~90)

typedef _Float16 half8 __attribute__((ext_vector_type(8)));
typedef float f32x4 __attribute__((ext_vector_type(4)));

// ---------------- bucketed CSR build (no node-grained global atomics) ----------------

__global__ __launch_bounds__(256) void bucket_init(int* __restrict__ bucket_cur) {
  int t = blockIdx.x * 256 + threadIdx.x;
  if (t < NBUK) bucket_cur[t] = t * BCAP;
}

// pass A: bin edges by dst>>9 into fixed-capacity segments; store packed (src<<9)|local
__global__ __launch_bounds__(256) void binA(const int* __restrict__ src,
                                            const int* __restrict__ dst,
                                            int* __restrict__ bucket_cur,
                                            unsigned* __restrict__ binned) {
  __shared__ int hist[NBUK];
  __shared__ int sc[256];
  __shared__ int lbase[NBUK];
  __shared__ int gbase[NBUK];
  __shared__ int lcur[NBUK];
  __shared__ uint2 stage[EPB];
  int t = threadIdx.x;
  int e0 = blockIdx.x * EPB;
  if (t < NBUK) hist[t] = 0;
  __syncthreads();
  int es[8], ed[8];
#pragma unroll
  for (int j = 0; j < 8; ++j) {
    int e = e0 + t + j * 256;
    if (e < NE) {
      es[j] = src[e];
      ed[j] = dst[e];
      atomicAdd(&hist[ed[j] >> 9], 1);
    } else {
      es[j] = -1;
      ed[j] = 0;
    }
  }
  __syncthreads();
  sc[t] = (t < NBUK) ? hist[t] : 0;
  __syncthreads();
  for (int off = 1; off < 256; off <<= 1) {
    int v = (t >= off) ? sc[t - off] : 0;
    __syncthreads();
    sc[t] += v;
    __syncthreads();
  }
  if (t < NBUK) {
    int h = hist[t];
    int lb = sc[t] - h;
    lbase[t] = lb;
    lcur[t] = lb;
    if (h > 0) gbase[t] = atomicAdd(&bucket_cur[t], h);
  }
  __syncthreads();
#pragma unroll
  for (int j = 0; j < 8; ++j) {
    if (es[j] >= 0) {
      int b = ed[j] >> 9;
      int slot = atomicAdd(&lcur[b], 1);
      stage[slot] = make_uint2((unsigned)es[j], (unsigned)ed[j]);
    }
  }
  __syncthreads();
  int total = min(EPB, NE - e0);
  for (int i = t; i < total; i += 256) {
    uint2 p = stage[i];
    int b = (int)(p.y >> 9);
    binned[(size_t)gbase[b] + (i - lbase[b])] = (p.x << 9) | (p.y & 511u);
  }
}

// scan bucket fill counts -> global bucket bases
__global__ __launch_bounds__(256) void bucket_scan(const int* __restrict__ bucket_cur,
                                                   int* __restrict__ bucket_base,
                                                   int* __restrict__ row_ptr) {
  __shared__ int part[256];
  int t = threadIdx.x;
  int v = (t < NBUK) ? (bucket_cur[t] - t * BCAP) : 0;
  part[t] = v;
  __syncthreads();
  for (int off = 1; off < 256; off <<= 1) {
    int u = (t >= off) ? part[t - off] : 0;
    __syncthreads();
    part[t] += u;
    __syncthreads();
  }
  if (t < NBUK) bucket_base[t] = part[t] - v;
  if (t == 0) row_ptr[NN] = NE;
}

// pass B: per bucket — per-node histogram + scan in LDS, write row_ptr/deg_inv/col coalesced
__global__ __launch_bounds__(256) void binB(const unsigned* __restrict__ binned,
                                            const int* __restrict__ bucket_cur,
                                            const int* __restrict__ bucket_base,
                                            int* __restrict__ row_ptr,
                                            float* __restrict__ deg_inv,
                                            int* __restrict__ col) {
  __shared__ int hist[NPB];
  __shared__ int cur2[NPB];
  __shared__ int part[256];
  __shared__ int srcS[BCAP];
  int b = blockIdx.x;
  int n0 = b * NPB;
  int n1 = min(n0 + NPB, NN);
  int cnt = bucket_cur[b] - b * BCAP;
  int gb = bucket_base[b];
  size_t seg = (size_t)b * BCAP;
  int t = threadIdx.x;
  hist[t] = 0;
  hist[t + 256] = 0;
  __syncthreads();
  for (int i = t; i < cnt; i += 256)
    atomicAdd(&hist[(int)(binned[seg + i] & 511u)], 1);
  __syncthreads();
  int c0 = hist[2 * t], c1 = hist[2 * t + 1];
  int s = c0 + c1;
  part[t] = s;
  __syncthreads();
  for (int off = 1; off < 256; off <<= 1) {
    int u = (t >= off) ? part[t - off] : 0;
    __syncthreads();
    part[t] += u;
    __syncthreads();
  }
  int excl = part[t] - s;
  cur2[2 * t] = excl;
  cur2[2 * t + 1] = excl + c0;
  int n = n0 + 2 * t;
  if (n < n1) {
    row_ptr[n] = gb + excl;
    deg_inv[n] = 1.0f / (float)(c0 > 1 ? c0 : 1);
  }
  if (n + 1 < n1) {
    row_ptr[n + 1] = gb + excl + c0;
    deg_inv[n + 1] = 1.0f / (float)(c1 > 1 ? c1 : 1);
  }
  __syncthreads();
  for (int i = t; i < cnt; i += 256) {
    unsigned p = binned[seg + i];
    int slot = atomicAdd(&cur2[(int)(p & 511u)], 1);
    srcS[slot] = (int)(p >> 9);
  }
  __syncthreads();
  for (int i = t; i < cnt; i += 256) col[(size_t)gb + i] = srcS[i];
}

// ---------------- x -> fp16 shadow ----------------

__global__ __launch_bounds__(256) void tohalf(const float* __restrict__ x,
                                              __half* __restrict__ x16) {
  size_t o = ((size_t)blockIdx.x * 256 + threadIdx.x) * 8;
  float4 a = *(const float4*)(x + o);
  float4 b = *(const float4*)(x + o + 4);
  union { uint4 u; __half h[8]; } U;
  U.h[0] = __float2half(a.x); U.h[1] = __float2half(a.y);
  U.h[2] = __float2half(a.z); U.h[3] = __float2half(a.w);
  U.h[4] = __float2half(b.x); U.h[5] = __float2half(b.y);
  U.h[6] = __float2half(b.z); U.h[7] = __float2half(b.w);
  *(uint4*)(x16 + o) = U.u;
}

// ---------------- weight prep: fp16 transposed B operands ----------------

__global__ __launch_bounds__(256) void prep_weights(const float* __restrict__ Wl,
                                                    const float* __restrict__ Wr,
                                                    const float* __restrict__ Wp,
                                                    _Float16* __restrict__ WcatT,
                                                    _Float16* __restrict__ WpT) {
  int t = blockIdx.x * 256 + threadIdx.x;
  if (t < 4 * 64 * 128) {
    int l = t >> 13, rem = t & 8191, j = rem >> 7, k = rem & 127;
    float v = (k < 64) ? Wl[l * 4096 + k * 64 + j] : Wr[l * 4096 + (k - 64) * 64 + j];
    WcatT[t] = (_Float16)v;
  }
  if (t < 4 * 32 * 64) {
    int l = t >> 11, rem = t & 2047, j = rem >> 6, k = rem & 63;
    WpT[t] = (_Float16)Wp[(size_t)(l * 64 + k) * 32 + j];
  }
}

// ---------------- fused layer: gather-mean (LDS) + MFMA GEMM + projection ----------------
// 64 nodes / 256-thread block (4 waves).
// Phase 1: wave-per-node gather, 16 nodes/wave -> aggS (fp16, PADA-padded).
// Phase 2: hn = [aggS|h] @ [Wl;Wr] + bl (MFMA); out (+)= hn @ Wp.
// mfma_f32_16x16x32_f16: A row=lane&15, k=(lane>>4)*8+i ; B col=lane&15 same k ;
// D col=lane&15, row=(lane>>4)*4+reg.  flags bit0: layer0; bit1: write hn16.

#define PADA 72  // aggS row stride (halves): 144B rows, 16B-aligned half8 reads
#define PADC 72

__global__ __launch_bounds__(256, 4) void fused_layer(
    const _Float16* __restrict__ h16,
    const int* __restrict__ row_ptr, const int* __restrict__ col,
    const float* __restrict__ deginv,
    const _Float16* __restrict__ WcatT, const float* __restrict__ bl,
    const _Float16* __restrict__ WpT, const float* __restrict__ bp,
    _Float16* __restrict__ hn16, float* __restrict__ out, int flags) {
  __shared__ _Float16 aggS[64 * PADA];
  __shared__ _Float16 cS[64 * PADC];
  int tid = threadIdx.x;
  int w = tid >> 6, l = tid & 63;
  int base = blockIdx.x * 64;

  // ---- phase 1: gather-mean, wave per node (lane = feature), 16 nodes/wave ----
  for (int i = 0; i < 16; ++i) {
    int n = base + (w << 4) + i;
    float acc = 0.f;
    if (n < NN) {
      int beg = row_ptr[n], end = row_ptr[n + 1];
      int e = beg;
      while (e < end) {
        int chunk = end - e;
        if (chunk > 64) chunk = 64;
        int cv = col[e + (l < chunk ? l : chunk - 1)];
        int q = 0;
        for (; q + 8 <= chunk; q += 8) {
          int s0 = __shfl(cv, q + 0, 64), s1 = __shfl(cv, q + 1, 64);
          int s2 = __shfl(cv, q + 2, 64), s3 = __shfl(cv, q + 3, 64);
          int s4 = __shfl(cv, q + 4, 64), s5 = __shfl(cv, q + 5, 64);
          int s6 = __shfl(cv, q + 6, 64), s7 = __shfl(cv, q + 7, 64);
          float v0 = (float)h16[(size_t)s0 * 64 + l];
          float v1 = (float)h16[(size_t)s1 * 64 + l];
          float v2 = (float)h16[(size_t)s2 * 64 + l];
          float v3 = (float)h16[(size_t)s3 * 64 + l];
          float v4 = (float)h16[(size_t)s4 * 64 + l];
          float v5 = (float)h16[(size_t)s5 * 64 + l];
          float v6 = (float)h16[(size_t)s6 * 64 + l];
          float v7 = (float)h16[(size_t)s7 * 64 + l];
          acc += ((v0 + v1) + (v2 + v3)) + ((v4 + v5) + (v6 + v7));
        }
        for (; q < chunk; ++q) {
          int s = __shfl(cv, q, 64);
          acc += (float)h16[(size_t)s * 64 + l];
        }
        e += chunk;
      }
      acc *= deginv[n];
    }
    aggS[((w << 4) + i) * PADA + l] = (_Float16)acc;
  }
  __syncthreads();

  // ---- phase 2: MFMA GEMM ----
  int lr = l & 15, lg = l >> 4;
  int arow = base + (w << 4) + lr;

  f32x4 acc4[4];
#pragma unroll
  for (int ct = 0; ct < 4; ++ct) {
    float b = bl[ct * 16 + lr];
    acc4[ct] = (f32x4){b, b, b, b};
  }
  const half8 a0 = *(const half8*)(aggS + ((w << 4) + lr) * PADA + lg * 8);
  const half8 a1 = *(const half8*)(aggS + ((w << 4) + lr) * PADA + 32 + lg * 8);
  const half8 a2 = *(const half8*)(h16 + (size_t)arow * 64 + lg * 8);
  const half8 a3 = *(const half8*)(h16 + (size_t)arow * 64 + 32 + lg * 8);
#pragma unroll
  for (int ct = 0; ct < 4; ++ct) {
    const _Float16* wb = WcatT + (ct * 16 + lr) * 128 + lg * 8;
    half8 b0 = *(const half8*)(wb);
    half8 b1 = *(const half8*)(wb + 32);
    half8 b2 = *(const half8*)(wb + 64);
    half8 b3 = *(const half8*)(wb + 96);
    acc4[ct] = __builtin_amdgcn_mfma_f32_16x16x32_f16(a0, b0, acc4[ct], 0, 0, 0);
    acc4[ct] = __builtin_amdgcn_mfma_f32_16x16x32_f16(a1, b1, acc4[ct], 0, 0, 0);
    acc4[ct] = __builtin_amdgcn_mfma_f32_16x16x32_f16(a2, b2, acc4[ct], 0, 0, 0);
    acc4[ct] = __builtin_amdgcn_mfma_f32_16x16x32_f16(a3, b3, acc4[ct], 0, 0, 0);
  }

  // stage hn tile to LDS (fp16): D-layout scatter
#pragma unroll
  for (int ct = 0; ct < 4; ++ct)
#pragma unroll
    for (int r = 0; r < 4; ++r)
      cS[((w << 4) + (lg << 2) + r) * PADC + ct * 16 + lr] = (_Float16)acc4[ct][r];
  __syncthreads();

  // coalesced hn16 write from LDS (skipped on last layer)
  if (flags & 2) {
#pragma unroll
    for (int j = 0; j < 2; ++j) {
      int idx = tid + j * 256;
      int row = idx >> 3, c8 = (idx & 7) * 8;
      *(half8*)(hn16 + (size_t)(base + row) * 64 + c8) =
          *(const half8*)(cS + row * PADC + c8);
    }
  }

  // projection: out(64x32) (+)= C(64x64) @ Wp(64x32)
  f32x4 pacc[2];
#pragma unroll
  for (int pt = 0; pt < 2; ++pt) {
    int colo = pt * 16 + lr;
    if (flags & 1) {
      float b = bp[colo];
      pacc[pt] = (f32x4){b, b, b, b};
    } else {
#pragma unroll
      for (int r = 0; r < 4; ++r) {
        int row = base + (w << 4) + (lg << 2) + r;
        pacc[pt][r] = (row < NN) ? out[(size_t)row * 32 + colo] : 0.f;
      }
    }
  }
  const _Float16* crow = cS + ((w << 4) + lr) * PADC + lg * 8;
  half8 c0 = *(const half8*)(crow);
  half8 c1 = *(const half8*)(crow + 32);
#pragma unroll
  for (int pt = 0; pt < 2; ++pt) {
    const _Float16* wp = WpT + (pt * 16 + lr) * 64 + lg * 8;
    half8 w0 = *(const half8*)(wp);
    half8 w1 = *(const half8*)(wp + 32);
    pacc[pt] = __builtin_amdgcn_mfma_f32_16x16x32_f16(c0, w0, pacc[pt], 0, 0, 0);
    pacc[pt] = __builtin_amdgcn_mfma_f32_16x16x32_f16(c1, w1, pacc[pt], 0, 0, 0);
  }
#pragma unroll
  for (int pt = 0; pt < 2; ++pt) {
    int colo = pt * 16 + lr;
#pragma unroll
    for (int r = 0; r < 4; ++r) {
      int row = base + (w << 4) + (lg << 2) + r;
      if (row < NN) out[(size_t)row * 32 + colo] = pacc[pt][r];
    }
  }
}

// ---------------- launch ----------------

extern "C" void kernel_launch(void* const* d_in, const int* in_sizes, int n_in,
                              void* d_out, int out_size, void* d_ws, size_t ws_size,
                              hipStream_t stream) {
  const float* x  = (const float*)d_in[0];
  const int*   ei = (const int*)d_in[1];   // [2, NE] int32
  const float* Wl = (const float*)d_in[2];
  const float* bl = (const float*)d_in[3];
  const float* Wr = (const float*)d_in[4];
  const float* Wp = (const float*)d_in[5];
  const float* bp = (const float*)d_in[6];
  float* out = (float*)d_out;

  char* ws = (char*)d_ws;
  size_t off = 0;
  auto alloc = [&](size_t bytes) {
    void* p = ws + off;
    off = (off + bytes + 255) & ~(size_t)255;
    return p;
  };
  int*      row_ptr     = (int*)alloc(((size_t)NN + 1) * 4);
  float*    deginv      = (float*)alloc((size_t)NN * 4);
  int*      col         = (int*)alloc((size_t)NE * 4);
  int*      bucket_cur  = (int*)alloc((size_t)NBUK * 4);
  int*      bucket_base = (int*)alloc((size_t)NBUK * 4);
  unsigned* binned      = (unsigned*)alloc((size_t)NBUK * BCAP * 4);
  __half*   x16         = (__half*)alloc((size_t)NNP * 64 * 2);
  __half*   h16A        = (__half*)alloc((size_t)NNP * 64 * 2);
  __half*   h16B        = (__half*)alloc((size_t)NNP * 64 * 2);
  _Float16* WcatT       = (_Float16*)alloc((size_t)4 * 64 * 128 * 2);
  _Float16* WpT         = (_Float16*)alloc((size_t)4 * 32 * 64 * 2);

  tohalf<<<3125, 256, 0, stream>>>(x, x16);
  prep_weights<<<128, 256, 0, stream>>>(Wl, Wr, Wp, WcatT, WpT);
  bucket_init<<<1, 256, 0, stream>>>(bucket_cur);
  binA<<<ABLK, 256, 0, stream>>>(ei, ei + NE, bucket_cur, binned);
  bucket_scan<<<1, 256, 0, stream>>>(bucket_cur, bucket_base, row_ptr);
  binB<<<NBUK, 256, 0, stream>>>(binned, bucket_cur, bucket_base, row_ptr, deginv, col);

  const __half* cur16 = x16;
  __half* bufs[2] = {h16A, h16B};
  int nblk = (NN + 63) / 64;  // 1563
  for (int l = 0; l < 4; ++l) {
    __half* nxt = bufs[l & 1];
    int flags = (l == 0 ? 1 : 0) | (l < 3 ? 2 : 0);
    fused_layer<<<nblk, 256, 0, stream>>>(
        (const _Float16*)cur16, row_ptr, col, deginv,
        WcatT + l * 8192, bl + l * 64, WpT + l * 2048, bp,
        (_Float16*)nxt, out, flags);
    cur16 = nxt;
  }
}